// Round 1
// baseline (413.352 us; speedup 1.0000x reference)
//
#include <hip/hip_runtime.h>
#include <cstddef>
#include <cstdint>

#define NN 6144
#define FF 512
#define HH 128
#define CCC 16
#define KTOP 50

// ---------------------------------------------------------------- reductions
__device__ __forceinline__ float wave_sum(float v) {
  #pragma unroll
  for (int o = 32; o; o >>= 1) v += __shfl_down(v, o);
  return v;
}

// ---------------------------------------------------------------- row sums of Adj
__global__ __launch_bounds__(256) void k_rowsum(const float* __restrict__ A,
                                                float* __restrict__ dinv,
                                                float* __restrict__ dsq) {
  const int row = blockIdx.x, t = threadIdx.x;
  const float4* Ar = (const float4*)(A + (size_t)row * NN);
  float s = 0.f;
  for (int j = t; j < NN / 4; j += 256) {
    float4 v = Ar[j];
    s += v.x + v.y + v.z + v.w;
  }
  s = wave_sum(s);
  __shared__ float sm[4];
  if ((t & 63) == 0) sm[t >> 6] = s;
  __syncthreads();
  if (t == 0) {
    float tot = sm[0] + sm[1] + sm[2] + sm[3];
    float dv = tot > 0.f ? 1.0f / sqrtf(tot) : 0.0f;
    dinv[row] = dv;
    dsq[row] = dv * dv;
  }
}

// ---------------------------------------------------------------- gate + e[] = exp(-u)
__global__ __launch_bounds__(256) void k_flag(const float* __restrict__ u,
                                              const float* __restrict__ delta,
                                              float* __restrict__ e,
                                              int* __restrict__ flag) {
  const int t = threadIdx.x;
  float emax = -1e30f, dmin = 1e30f;
  for (int j = t; j < NN; j += 256) {
    float ev = expf(-u[j]);
    e[j] = ev;
    emax = fmaxf(emax, ev);
    dmin = fminf(dmin, delta[j]);
  }
  #pragma unroll
  for (int o = 32; o; o >>= 1) {
    emax = fmaxf(emax, __shfl_down(emax, o));
    dmin = fminf(dmin, __shfl_down(dmin, o));
  }
  __shared__ float sm[4], sn[4];
  if ((t & 63) == 0) { sm[t >> 6] = emax; sn[t >> 6] = dmin; }
  __syncthreads();
  if (t == 0) {
    emax = fmaxf(fmaxf(sm[0], sm[1]), fmaxf(sm[2], sm[3]));
    dmin = fminf(fminf(sn[0], sn[1]), fminf(sn[2], sn[3]));
    flag[0] = (emax >= dmin || dmin <= 0.0f) ? 1 : 0;
  }
}

// ---------------------------------------------------------------- gated: X1 = dinv (.) input (.) w1
__global__ __launch_bounds__(256) void k_prescale(const float* __restrict__ in,
                                                  const float* __restrict__ dinv,
                                                  const float* __restrict__ w1,
                                                  float* __restrict__ X1,
                                                  const int* __restrict__ gate) {
  if (gate[0] == 0) return;
  const int idx = blockIdx.x * 256 + threadIdx.x;           // float4 index
  const int f4 = idx % (FF / 4), i = idx / (FF / 4);
  float4 v = ((const float4*)in)[idx];
  float4 w = ((const float4*)w1)[f4];
  const float d = dinv[i];
  v.x *= d * w.x; v.y *= d * w.y; v.z *= d * w.z; v.w *= d * w.w;
  ((float4*)X1)[idx] = v;
}

// ---------------------------------------------------------------- epilogue helper
template <int MODE>
__device__ __forceinline__ float epi(float v, int r, int c,
                                     const float* rs, const float* cs, const float* bias) {
  if constexpr (MODE == 1) return v * rs[r];
  if constexpr (MODE == 2) return v * rs[r] * cs[c];
  if constexpr (MODE == 3) { float o = v * rs[r] + bias[c]; return o > 0.f ? o : 0.f; }
  if constexpr (MODE == 4) return v * rs[r] + bias[c];
  return v;
}

// ---------------------------------------------------------------- generic fp32 GEMM  C = A @ X
// BM=64, BK=32, BN in {128,16}. SPLIT: write raw partials per blockIdx.z slot.
template <int BN, int MODE, bool GATED, bool SPLIT>
__global__ __launch_bounds__(256) void k_gemm(const float* __restrict__ A,
                                              const float* __restrict__ X,
                                              float* __restrict__ C,
                                              const float* __restrict__ rs,
                                              const float* __restrict__ cs,
                                              const float* __restrict__ bias,
                                              int M, int K, int NC,
                                              const int* __restrict__ gate) {
  if (GATED && gate[0] == 0) return;
  constexpr int BM = 64, BK = 32;
  constexpr int TN = (BN == 128) ? 8 : 1;
  const int row0 = blockIdx.x * BM;
  const int col0 = blockIdx.y * BN;
  int kbeg = 0, kend = K;
  if (SPLIT) { const int klen = K / gridDim.z; kbeg = blockIdx.z * klen; kend = kbeg + klen; }
  __shared__ float As[BM][BK + 1];
  __shared__ float Xs[BK][BN];
  const int t = threadIdx.x;
  const int tx = t & 15, ty = t >> 4;
  float acc[4][TN];
  #pragma unroll
  for (int i = 0; i < 4; ++i)
    #pragma unroll
    for (int j = 0; j < TN; ++j) acc[i][j] = 0.f;

  for (int k0 = kbeg; k0 < kend; k0 += BK) {
    // stage A tile (64x32)
    #pragma unroll
    for (int s = t; s < BM * BK / 4; s += 256) {
      const int r = s >> 3, q = s & 7;
      float4 v = *(const float4*)(A + (size_t)(row0 + r) * K + k0 + q * 4);
      As[r][q * 4 + 0] = v.x; As[r][q * 4 + 1] = v.y;
      As[r][q * 4 + 2] = v.z; As[r][q * 4 + 3] = v.w;
    }
    // stage X tile (32xBN)
    for (int s = t; s < BK * BN / 4; s += 256) {
      const int r = s / (BN / 4), q = s % (BN / 4);
      *(float4*)&Xs[r][q * 4] = *(const float4*)(X + (size_t)(k0 + r) * NC + col0 + q * 4);
    }
    __syncthreads();
    #pragma unroll
    for (int kk = 0; kk < BK; ++kk) {
      float a[4];
      #pragma unroll
      for (int i = 0; i < 4; ++i) a[i] = As[ty * 4 + i][kk];
      if constexpr (BN == 128) {
        float4 x0 = *(float4*)&Xs[kk][tx * 8];
        float4 x1 = *(float4*)&Xs[kk][tx * 8 + 4];
        #pragma unroll
        for (int i = 0; i < 4; ++i) {
          acc[i][0] += a[i] * x0.x; acc[i][1] += a[i] * x0.y;
          acc[i][2] += a[i] * x0.z; acc[i][3] += a[i] * x0.w;
          acc[i][4] += a[i] * x1.x; acc[i][5] += a[i] * x1.y;
          acc[i][6] += a[i] * x1.z; acc[i][7] += a[i] * x1.w;
        }
      } else {
        const float xv = Xs[kk][tx];
        #pragma unroll
        for (int i = 0; i < 4; ++i) acc[i][0] += a[i] * xv;
      }
    }
    __syncthreads();
  }

  if constexpr (SPLIT) {
    float* P = C + (size_t)blockIdx.z * M * NC;
    #pragma unroll
    for (int i = 0; i < 4; ++i)
      #pragma unroll
      for (int j = 0; j < TN; ++j)
        P[(size_t)(row0 + ty * 4 + i) * NC + col0 + tx * TN + j] = acc[i][j];
  } else {
    #pragma unroll
    for (int i = 0; i < 4; ++i)
      #pragma unroll
      for (int j = 0; j < TN; ++j) {
        const int r = row0 + ty * 4 + i, c = col0 + tx * TN + j;
        C[(size_t)r * NC + c] = epi<MODE>(acc[i][j], r, c, rs, cs, bias);
      }
  }
}

// ---------------------------------------------------------------- split-K reduce + epilogue
template <int MODE>
__global__ __launch_bounds__(256) void k_reduce(const float* __restrict__ P,
                                                float* __restrict__ C,
                                                const float* __restrict__ rs,
                                                const float* __restrict__ cs,
                                                const float* __restrict__ bias,
                                                int M, int NC, int S) {
  const size_t idx = (size_t)blockIdx.x * 256 + threadIdx.x;
  const size_t tot = (size_t)M * NC;
  float s = 0.f;
  for (int p = 0; p < S; ++p) s += P[p * tot + idx];
  const int r = (int)(idx / NC), c = (int)(idx % NC);
  C[idx] = epi<MODE>(s, r, c, rs, cs, bias);
}

// ---------------------------------------------------------------- gated: row-normalize embeddings
__global__ __launch_bounds__(256) void k_normalize(const float* __restrict__ embp,
                                                   const float* __restrict__ dinv,
                                                   float* __restrict__ embn,
                                                   const int* __restrict__ gate) {
  if (gate[0] == 0) return;
  const int row = blockIdx.x, t = threadIdx.x;
  const float d = dinv[row];
  const float v0 = embp[(size_t)row * FF + t] * d;
  const float v1 = embp[(size_t)row * FF + 256 + t] * d;
  float ss = wave_sum(v0 * v0 + v1 * v1);
  __shared__ float sm[4];
  __shared__ float inv_s;
  if ((t & 63) == 0) sm[t >> 6] = ss;
  __syncthreads();
  if (t == 0) {
    const float nrm = sqrtf(sm[0] + sm[1] + sm[2] + sm[3]);
    inv_s = 1.0f / fmaxf(nrm, 1e-12f);
  }
  __syncthreads();
  const float inv = inv_s;
  embn[(size_t)row * FF + t] = v0 * inv;
  embn[(size_t)row * FF + 256 + t] = v1 * inv;
}

// ---------------------------------------------------------------- gated: sim = U @ U^T (64x64 tiles)
__global__ __launch_bounds__(256) void k_sim(const float* __restrict__ U,
                                             float* __restrict__ S,
                                             const int* __restrict__ gate) {
  if (gate[0] == 0) return;
  const int bi = blockIdx.x * 64, bj = blockIdx.y * 64;
  __shared__ float Ui[64][33], Uj[64][33];
  const int t = threadIdx.x, tx = t & 15, ty = t >> 4;
  float acc[4][4];
  #pragma unroll
  for (int i = 0; i < 4; ++i)
    #pragma unroll
    for (int j = 0; j < 4; ++j) acc[i][j] = 0.f;
  for (int k0 = 0; k0 < FF; k0 += 32) {
    #pragma unroll
    for (int s = t; s < 512; s += 256) {
      const int r = s >> 3, q = s & 7;
      float4 v = *(const float4*)(U + (size_t)(bi + r) * FF + k0 + q * 4);
      Ui[r][q * 4 + 0] = v.x; Ui[r][q * 4 + 1] = v.y; Ui[r][q * 4 + 2] = v.z; Ui[r][q * 4 + 3] = v.w;
      float4 w = *(const float4*)(U + (size_t)(bj + r) * FF + k0 + q * 4);
      Uj[r][q * 4 + 0] = w.x; Uj[r][q * 4 + 1] = w.y; Uj[r][q * 4 + 2] = w.z; Uj[r][q * 4 + 3] = w.w;
    }
    __syncthreads();
    #pragma unroll
    for (int kk = 0; kk < 32; ++kk) {
      float a[4], b[4];
      #pragma unroll
      for (int i = 0; i < 4; ++i) a[i] = Ui[ty * 4 + i][kk];
      #pragma unroll
      for (int j = 0; j < 4; ++j) b[j] = Uj[tx * 4 + j][kk];
      #pragma unroll
      for (int i = 0; i < 4; ++i)
        #pragma unroll
        for (int j = 0; j < 4; ++j) acc[i][j] += a[i] * b[j];
    }
    __syncthreads();
  }
  #pragma unroll
  for (int i = 0; i < 4; ++i)
    #pragma unroll
    for (int j = 0; j < 4; ++j)
      S[(size_t)(bi + ty * 4 + i) * NN + bj + tx * 4 + j] = acc[i][j];
}

// ---------------------------------------------------------------- gated: top-50 per row
__global__ __launch_bounds__(256) void k_topk(const float* __restrict__ sim,
                                              float* __restrict__ vals,
                                              int* __restrict__ idxo,
                                              const int* __restrict__ gate) {
  if (gate[0] == 0) return;
  const int row = blockIdx.x, t = threadIdx.x;
  __shared__ float sv[NN];
  __shared__ float bw[4];
  __shared__ int bj4[4];
  const float* sr = sim + (size_t)row * NN;
  for (int j = t; j < NN; j += 256) sv[j] = sr[j];
  __syncthreads();
  for (int it = 0; it < KTOP; ++it) {
    float bv = -3.4e38f; int bj = NN;
    for (int j = t; j < NN; j += 256) {
      const float v = sv[j];
      if (v > bv || (v == bv && j < bj)) { bv = v; bj = j; }
    }
    #pragma unroll
    for (int o = 32; o; o >>= 1) {
      const float ov = __shfl_down(bv, o);
      const int oj = __shfl_down(bj, o);
      if (ov > bv || (ov == bv && oj < bj)) { bv = ov; bj = oj; }
    }
    if ((t & 63) == 0) { bw[t >> 6] = bv; bj4[t >> 6] = bj; }
    __syncthreads();
    if (t == 0) {
      #pragma unroll
      for (int q = 1; q < 4; ++q)
        if (bw[q] > bv || (bw[q] == bv && bj4[q] < bj)) { bv = bw[q]; bj = bj4[q]; }
      vals[row * KTOP + it] = bv;
      idxo[row * KTOP + it] = bj;
      sv[bj] = -3.4e38f;
    }
    __syncthreads();
  }
}

// ---------------------------------------------------------------- gated: zero A_new region
__global__ __launch_bounds__(256) void k_zero(float* __restrict__ p, const int* __restrict__ gate) {
  if (gate[0] == 0) return;
  const size_t i = (size_t)blockIdx.x * 256 + threadIdx.x;
  ((float4*)p)[i] = float4{0.f, 0.f, 0.f, 0.f};
}

// ---------------------------------------------------------------- gated: scatter-symmetrize
__global__ __launch_bounds__(256) void k_scatter(const float* __restrict__ vals,
                                                 const int* __restrict__ idx,
                                                 float* __restrict__ anew,
                                                 const int* __restrict__ gate) {
  if (gate[0] == 0) return;
  const int tid = blockIdx.x * 256 + threadIdx.x;
  if (tid >= NN * KTOP) return;
  const int i = tid / KTOP;
  const float v = vals[tid] * 0.5f;
  const int j = idx[tid];
  atomicAdd(anew + (size_t)i * NN + j, v);
  atomicAdd(anew + (size_t)j * NN + i, v);
}

// ---------------------------------------------------------------- mask + fuse + row sums (always)
__device__ __forceinline__ float maskval(float a, float ev, float di, float m0) {
  if (a > 0.0f) {
    const float w = 2.0f / (1.0f + expf(di - ev));
    return (w >= 1.0f) ? a * w : 0.0f;
  }
  return a * m0;
}

__global__ __launch_bounds__(256) void k_mask_final(float* __restrict__ anew,
                                                    const float* __restrict__ adj,
                                                    const float* __restrict__ e,
                                                    const float* __restrict__ delta,
                                                    float* __restrict__ afin,
                                                    float* __restrict__ dinv2f,
                                                    const int* __restrict__ gate) {
  const int row = blockIdx.x, t = threadIdx.x;
  const bool fl = gate[0] != 0;
  const float di = delta[row];
  const float w0 = 2.0f / (1.0f + expf(di));
  const float m0 = (w0 >= 1.0f) ? w0 : 0.0f;
  const float4* ar = (const float4*)(adj + (size_t)row * NN);
  float4* an = (float4*)(anew + (size_t)row * NN);
  float4* af = (float4*)(afin + (size_t)row * NN);
  const float4* ef = (const float4*)e;
  float s = 0.f;
  for (int q = t; q < NN / 4; q += 256) {
    float4 a = fl ? an[q] : float4{0.f, 0.f, 0.f, 0.f};
    const float4 ad = ar[q];
    const float4 ev = ef[q];
    float4 ao, fo;
    ao.x = maskval(a.x, ev.x, di, m0); fo.x = ao.x + ad.x;
    ao.y = maskval(a.y, ev.y, di, m0); fo.y = ao.y + ad.y;
    ao.z = maskval(a.z, ev.z, di, m0); fo.z = ao.z + ad.z;
    ao.w = maskval(a.w, ev.w, di, m0); fo.w = ao.w + ad.w;
    s += fo.x + fo.y + fo.z + fo.w;
    an[q] = ao;
    af[q] = fo;
  }
  s = wave_sum(s);
  __shared__ float sm[4];
  if ((t & 63) == 0) sm[t >> 6] = s;
  __syncthreads();
  if (t == 0) {
    const float tot = sm[0] + sm[1] + sm[2] + sm[3];
    dinv2f[row] = tot > 0.f ? 1.0f / sqrtf(tot) : 0.0f;
  }
}

// ---------------------------------------------------------------- launcher
extern "C" void kernel_launch(void* const* d_in, const int* in_sizes, int n_in,
                              void* d_out, int out_size, void* d_ws, size_t ws_size,
                              hipStream_t stream) {
  const float* input = (const float*)d_in[0];
  const float* Adj   = (const float*)d_in[1];
  const float* unc   = (const float*)d_in[2];
  const float* w1    = (const float*)d_in[3];
  const float* w2    = (const float*)d_in[4];
  const float* delta = (const float*)d_in[5];
  const float* W1    = (const float*)d_in[6];
  const float* b1    = (const float*)d_in[7];
  const float* W2    = (const float*)d_in[8];
  const float* b2    = (const float*)d_in[9];

  float* xout = (float*)d_out;
  float* anew = xout + (size_t)NN * CCC;
  float* afin = anew + (size_t)NN * NN;

  float* w = (float*)d_ws;
  size_t o = 0;
  float* DINV  = w + o; o += NN;
  float* DSQ   = w + o; o += NN;
  float* EARR  = w + o; o += NN;
  float* DINV2 = w + o; o += NN;
  int*   FLAG  = (int*)(w + o); o += NN;
  float* X1    = w + o; o += (size_t)NN * FF;
  float* X2    = w + o; o += (size_t)NN * FF;
  float* EMBP  = w + o; o += (size_t)NN * FF;
  float* EMBN  = w + o; o += (size_t)NN * FF;
  float* VALS  = w + o; o += (size_t)NN * KTOP;
  int*   IDX   = (int*)(w + o); o += (size_t)NN * KTOP;
  float* Y1    = w + o; o += (size_t)NN * HH;
  float* XRELU = w + o; o += (size_t)NN * HH;
  float* Y2    = w + o; o += (size_t)NN * CCC;
  float* PK    = w + o; o += (size_t)8 * NN * HH;   // split-K partials (max 8*6144*128)

  // 1. degrees of Adj
  k_rowsum<<<NN, 256, 0, stream>>>(Adj, DINV, DSQ);
  // 2. gate + e = exp(-u)
  k_flag<<<1, 256, 0, stream>>>(unc, delta, EARR, FLAG);

  // ---- gated graph-revision chain (dead unless some exp(-u_j) >= min delta) ----
  k_prescale<<<(NN * FF / 4) / 256, 256, 0, stream>>>(input, DINV, w1, X1, FLAG);
  k_gemm<128, 2, true, false><<<dim3(96, 4, 1), 256, 0, stream>>>(Adj, X1, X2, DSQ, w2, nullptr, NN, NN, FF, FLAG);
  k_gemm<128, 0, true, false><<<dim3(96, 4, 1), 256, 0, stream>>>(Adj, X2, EMBP, nullptr, nullptr, nullptr, NN, NN, FF, FLAG);
  k_normalize<<<NN, 256, 0, stream>>>(EMBP, DINV, EMBN, FLAG);
  k_sim<<<dim3(96, 96, 1), 256, 0, stream>>>(EMBN, afin, FLAG);            // sim scratch in A_final region
  k_topk<<<NN, 256, 0, stream>>>(afin, VALS, IDX, FLAG);
  k_zero<<<(NN * (size_t)NN / 4) / 256, 256, 0, stream>>>(anew, FLAG);
  k_scatter<<<(NN * KTOP + 255) / 256, 256, 0, stream>>>(VALS, IDX, anew, FLAG);

  // ---- mask, fuse with Adj, row sums of A_final (always; exact in both branches) ----
  k_mask_final<<<NN, 256, 0, stream>>>(anew, Adj, EARR, delta, afin, DINV2, FLAG);

  // ---- task GCN: x = Afn @ relu(Afn @ (input@W1) + b1) @ ... with D^-1/2 folded ----
  // Y1 = dinv2 (.) (input @ W1)      [6144x128], split-K=4
  k_gemm<128, 0, false, true><<<dim3(96, 1, 4), 256, 0, stream>>>(input, W1, PK, nullptr, nullptr, nullptr, NN, FF, HH, nullptr);
  k_reduce<1><<<(NN * HH) / 256, 256, 0, stream>>>(PK, Y1, DINV2, nullptr, nullptr, NN, HH, 4);
  // XRELU = relu(dinv2 (.) (A_final @ Y1) + b1), split-K=8
  k_gemm<128, 0, false, true><<<dim3(96, 1, 8), 256, 0, stream>>>(afin, Y1, PK, nullptr, nullptr, nullptr, NN, NN, HH, nullptr);
  k_reduce<3><<<(NN * HH) / 256, 256, 0, stream>>>(PK, XRELU, DINV2, nullptr, b1, NN, HH, 8);
  // Y2 = dinv2 (.) (XRELU @ W2)     [6144x16]
  k_gemm<16, 1, false, false><<<dim3(96, 1, 1), 256, 0, stream>>>(XRELU, W2, Y2, DINV2, nullptr, nullptr, NN, HH, CCC, nullptr);
  // x = dinv2 (.) (A_final @ Y2) + b2, split-K=8
  k_gemm<16, 0, false, true><<<dim3(96, 1, 8), 256, 0, stream>>>(afin, Y2, PK, nullptr, nullptr, nullptr, NN, NN, CCC, nullptr);
  k_reduce<4><<<(NN * CCC) / 256, 256, 0, stream>>>(PK, xout, DINV2, nullptr, b2, NN, CCC, 8);
}

// Round 3
// 295.851 us; speedup vs baseline: 1.3972x; 1.3972x over previous
//
#include <hip/hip_runtime.h>
#include <cstddef>
#include <cstdint>

#define NN 6144
#define FF 512
#define HH 128
#define CCC 16
#define KTOP 50

typedef __attribute__((ext_vector_type(8))) short bf16x8;
typedef __attribute__((ext_vector_type(4))) float f32x4;
typedef __attribute__((ext_vector_type(4))) ushort u16x4;

// ---------------------------------------------------------------- helpers
__device__ __forceinline__ float wave_sum(float v) {
  #pragma unroll
  for (int o = 32; o; o >>= 1) v += __shfl_down(v, o);
  return v;
}

__device__ __forceinline__ ushort f2b(float x) {   // fp32 -> bf16 RNE
  union { float f; uint32_t u; } v; v.f = x;
  const uint32_t r = v.u + 0x7FFFu + ((v.u >> 16) & 1u);
  return (ushort)(r >> 16);
}

// ---------------------------------------------------------------- gated: row sums of Adj
__global__ __launch_bounds__(256) void k_rowsum(const float* __restrict__ A,
                                                float* __restrict__ dinv,
                                                float* __restrict__ dsq,
                                                const int* __restrict__ gate) {
  if (gate[0] == 0) return;
  const int row = blockIdx.x, t = threadIdx.x;
  const float4* Ar = (const float4*)(A + (size_t)row * NN);
  float s = 0.f;
  for (int j = t; j < NN / 4; j += 256) {
    float4 v = Ar[j];
    s += v.x + v.y + v.z + v.w;
  }
  s = wave_sum(s);
  __shared__ float sm[4];
  if ((t & 63) == 0) sm[t >> 6] = s;
  __syncthreads();
  if (t == 0) {
    float tot = sm[0] + sm[1] + sm[2] + sm[3];
    float dv = tot > 0.f ? 1.0f / sqrtf(tot) : 0.0f;
    dinv[row] = dv;
    dsq[row] = dv * dv;
  }
}

// ---------------------------------------------------------------- gate + e[] = exp(-u)
__global__ __launch_bounds__(256) void k_flag(const float* __restrict__ u,
                                              const float* __restrict__ delta,
                                              float* __restrict__ e,
                                              int* __restrict__ flag) {
  const int t = threadIdx.x;
  float emax = -1e30f, dmin = 1e30f;
  for (int j = t; j < NN; j += 256) {
    float ev = expf(-u[j]);
    e[j] = ev;
    emax = fmaxf(emax, ev);
    dmin = fminf(dmin, delta[j]);
  }
  #pragma unroll
  for (int o = 32; o; o >>= 1) {
    emax = fmaxf(emax, __shfl_down(emax, o));
    dmin = fminf(dmin, __shfl_down(dmin, o));
  }
  __shared__ float sm[4], sn[4];
  if ((t & 63) == 0) { sm[t >> 6] = emax; sn[t >> 6] = dmin; }
  __syncthreads();
  if (t == 0) {
    emax = fmaxf(fmaxf(sm[0], sm[1]), fmaxf(sm[2], sm[3]));
    dmin = fminf(fminf(sn[0], sn[1]), fminf(sn[2], sn[3]));
    flag[0] = (emax >= dmin || dmin <= 0.0f) ? 1 : 0;
  }
}

// ---------------------------------------------------------------- gated: X1 = dinv (.) input (.) w1
__global__ __launch_bounds__(256) void k_prescale(const float* __restrict__ in,
                                                  const float* __restrict__ dinv,
                                                  const float* __restrict__ w1,
                                                  float* __restrict__ X1,
                                                  const int* __restrict__ gate) {
  if (gate[0] == 0) return;
  const int idx = blockIdx.x * 256 + threadIdx.x;           // float4 index
  const int f4 = idx % (FF / 4), i = idx / (FF / 4);
  float4 v = ((const float4*)in)[idx];
  float4 w = ((const float4*)w1)[f4];
  const float d = dinv[i];
  v.x *= d * w.x; v.y *= d * w.y; v.z *= d * w.z; v.w *= d * w.w;
  ((float4*)X1)[idx] = v;
}

// ---------------------------------------------------------------- epilogue helper
template <int MODE>
__device__ __forceinline__ float epi(float v, int r, int c,
                                     const float* rs, const float* cs, const float* bias) {
  if constexpr (MODE == 1) return v * rs[r];
  if constexpr (MODE == 2) return v * rs[r] * cs[c];
  if constexpr (MODE == 3) { float o = v * rs[r] + bias[c]; return o > 0.f ? o : 0.f; }
  if constexpr (MODE == 4) return v * rs[r] + bias[c];
  return v;
}

// ---------------------------------------------------------------- generic fp32 GEMM  C = A @ X
template <int BN, int MODE, bool GATED, bool SPLIT>
__global__ __launch_bounds__(256) void k_gemm(const float* __restrict__ A,
                                              const float* __restrict__ X,
                                              float* __restrict__ C,
                                              const float* __restrict__ rs,
                                              const float* __restrict__ cs,
                                              const float* __restrict__ bias,
                                              int M, int K, int NC,
                                              const int* __restrict__ gate) {
  if (GATED && gate[0] == 0) return;
  constexpr int BM = 64, BK = 32;
  constexpr int TN = (BN == 128) ? 8 : 1;
  const int row0 = blockIdx.x * BM;
  const int col0 = blockIdx.y * BN;
  int kbeg = 0, kend = K;
  if (SPLIT) { const int klen = K / gridDim.z; kbeg = blockIdx.z * klen; kend = kbeg + klen; }
  __shared__ float As[BM][BK + 1];
  __shared__ float Xs[BK][BN];
  const int t = threadIdx.x;
  const int tx = t & 15, ty = t >> 4;
  float acc[4][TN];
  #pragma unroll
  for (int i = 0; i < 4; ++i)
    #pragma unroll
    for (int j = 0; j < TN; ++j) acc[i][j] = 0.f;

  for (int k0 = kbeg; k0 < kend; k0 += BK) {
    #pragma unroll
    for (int s = t; s < BM * BK / 4; s += 256) {
      const int r = s >> 3, q = s & 7;
      float4 v = *(const float4*)(A + (size_t)(row0 + r) * K + k0 + q * 4);
      As[r][q * 4 + 0] = v.x; As[r][q * 4 + 1] = v.y;
      As[r][q * 4 + 2] = v.z; As[r][q * 4 + 3] = v.w;
    }
    for (int s = t; s < BK * BN / 4; s += 256) {
      const int r = s / (BN / 4), q = s % (BN / 4);
      *(float4*)&Xs[r][q * 4] = *(const float4*)(X + (size_t)(k0 + r) * NC + col0 + q * 4);
    }
    __syncthreads();
    #pragma unroll
    for (int kk = 0; kk < BK; ++kk) {
      float a[4];
      #pragma unroll
      for (int i = 0; i < 4; ++i) a[i] = As[ty * 4 + i][kk];
      if constexpr (BN == 128) {
        float4 x0 = *(float4*)&Xs[kk][tx * 8];
        float4 x1 = *(float4*)&Xs[kk][tx * 8 + 4];
        #pragma unroll
        for (int i = 0; i < 4; ++i) {
          acc[i][0] += a[i] * x0.x; acc[i][1] += a[i] * x0.y;
          acc[i][2] += a[i] * x0.z; acc[i][3] += a[i] * x0.w;
          acc[i][4] += a[i] * x1.x; acc[i][5] += a[i] * x1.y;
          acc[i][6] += a[i] * x1.z; acc[i][7] += a[i] * x1.w;
        }
      } else {
        const float xv = Xs[kk][tx];
        #pragma unroll
        for (int i = 0; i < 4; ++i) acc[i][0] += a[i] * xv;
      }
    }
    __syncthreads();
  }

  if constexpr (SPLIT) {
    float* P = C + (size_t)blockIdx.z * M * NC;
    #pragma unroll
    for (int i = 0; i < 4; ++i)
      #pragma unroll
      for (int j = 0; j < TN; ++j)
        P[(size_t)(row0 + ty * 4 + i) * NC + col0 + tx * TN + j] = acc[i][j];
  } else {
    #pragma unroll
    for (int i = 0; i < 4; ++i)
      #pragma unroll
      for (int j = 0; j < TN; ++j) {
        const int r = row0 + ty * 4 + i, c = col0 + tx * TN + j;
        C[(size_t)r * NC + c] = epi<MODE>(acc[i][j], r, c, rs, cs, bias);
      }
  }
}

// ---------------------------------------------------------------- split-K reduce + epilogue (+optional bf16 B^T emit)
template <int MODE>
__global__ __launch_bounds__(256) void k_reduce(const float* __restrict__ P,
                                                float* __restrict__ C,
                                                const float* __restrict__ rs,
                                                const float* __restrict__ cs,
                                                const float* __restrict__ bias,
                                                int M, int NC, int S,
                                                ushort* __restrict__ bt) {
  const size_t idx = (size_t)blockIdx.x * 256 + threadIdx.x;
  const size_t tot = (size_t)M * NC;
  float s = 0.f;
  for (int p = 0; p < S; ++p) s += P[p * tot + idx];
  const int r = (int)(idx / NC), c = (int)(idx % NC);
  const float v = epi<MODE>(s, r, c, rs, cs, bias);
  C[idx] = v;
  if (bt) bt[(size_t)c * M + r] = f2b(v);
}

// ---------------------------------------------------------------- MFMA bf16 GEMM: P[z] += A[6144x6144] @ BT^T
// A row-major bf16, BT row-major [NC][6144] bf16, split-K partials fp32.
template <int NC, int SPLITS>
__global__ __launch_bounds__(256) void k_mfma(const ushort* __restrict__ A,
                                              const ushort* __restrict__ BT,
                                              float* __restrict__ P) {
  const int wave = threadIdx.x >> 6, lane = threadIdx.x & 63;
  const int m0 = blockIdx.x * 64 + wave * 16;
  const int kbeg = blockIdx.z * (NN / SPLITS);
  const int r = lane & 15, kg = lane >> 4;          // row-in-tile, k-group
  constexpr int NB = NC / 16;
  f32x4 acc[NB];
  #pragma unroll
  for (int i = 0; i < NB; ++i) acc[i] = f32x4{0.f, 0.f, 0.f, 0.f};
  const ushort* a_ptr = A + (size_t)(m0 + r) * NN + kbeg + kg * 8;
  const ushort* b_ptr = BT + (size_t)r * NN + kbeg + kg * 8;
  #pragma unroll 4
  for (int k = 0; k < NN / SPLITS; k += 32) {
    const bf16x8 av = *(const bf16x8*)(a_ptr + k);
    #pragma unroll
    for (int nb = 0; nb < NB; ++nb) {
      const bf16x8 bv = *(const bf16x8*)(b_ptr + (size_t)nb * 16 * NN + k);
      acc[nb] = __builtin_amdgcn_mfma_f32_16x16x32_bf16(av, bv, acc[nb], 0, 0, 0);
    }
  }
  float* Pz = P + (size_t)blockIdx.z * NN * NC;
  #pragma unroll
  for (int nb = 0; nb < NB; ++nb)
    #pragma unroll
    for (int i = 0; i < 4; ++i)
      Pz[(size_t)(m0 + kg * 4 + i) * NC + nb * 16 + r] = acc[nb][i];
}

// ---------------------------------------------------------------- gated: row-normalize embeddings
__global__ __launch_bounds__(256) void k_normalize(const float* __restrict__ embp,
                                                   const float* __restrict__ dinv,
                                                   float* __restrict__ embn,
                                                   const int* __restrict__ gate) {
  if (gate[0] == 0) return;
  const int row = blockIdx.x, t = threadIdx.x;
  const float d = dinv[row];
  const float v0 = embp[(size_t)row * FF + t] * d;
  const float v1 = embp[(size_t)row * FF + 256 + t] * d;
  float ss = wave_sum(v0 * v0 + v1 * v1);
  __shared__ float sm[4];
  __shared__ float inv_s;
  if ((t & 63) == 0) sm[t >> 6] = ss;
  __syncthreads();
  if (t == 0) {
    const float nrm = sqrtf(sm[0] + sm[1] + sm[2] + sm[3]);
    inv_s = 1.0f / fmaxf(nrm, 1e-12f);
  }
  __syncthreads();
  const float inv = inv_s;
  embn[(size_t)row * FF + t] = v0 * inv;
  embn[(size_t)row * FF + 256 + t] = v1 * inv;
}

// ---------------------------------------------------------------- gated: sim = U @ U^T (64x64 tiles)
__global__ __launch_bounds__(256) void k_sim(const float* __restrict__ U,
                                             float* __restrict__ S,
                                             const int* __restrict__ gate) {
  if (gate[0] == 0) return;
  const int bi = blockIdx.x * 64, bj = blockIdx.y * 64;
  __shared__ float Ui[64][33], Uj[64][33];
  const int t = threadIdx.x, tx = t & 15, ty = t >> 4;
  float acc[4][4];
  #pragma unroll
  for (int i = 0; i < 4; ++i)
    #pragma unroll
    for (int j = 0; j < 4; ++j) acc[i][j] = 0.f;
  for (int k0 = 0; k0 < FF; k0 += 32) {
    #pragma unroll
    for (int s = t; s < 512; s += 256) {
      const int r = s >> 3, q = s & 7;
      float4 v = *(const float4*)(U + (size_t)(bi + r) * FF + k0 + q * 4);
      Ui[r][q * 4 + 0] = v.x; Ui[r][q * 4 + 1] = v.y; Ui[r][q * 4 + 2] = v.z; Ui[r][q * 4 + 3] = v.w;
      float4 w = *(const float4*)(U + (size_t)(bj + r) * FF + k0 + q * 4);
      Uj[r][q * 4 + 0] = w.x; Uj[r][q * 4 + 1] = w.y; Uj[r][q * 4 + 2] = w.z; Uj[r][q * 4 + 3] = w.w;
    }
    __syncthreads();
    #pragma unroll
    for (int kk = 0; kk < 32; ++kk) {
      float a[4], b[4];
      #pragma unroll
      for (int i = 0; i < 4; ++i) a[i] = Ui[ty * 4 + i][kk];
      #pragma unroll
      for (int j = 0; j < 4; ++j) b[j] = Uj[tx * 4 + j][kk];
      #pragma unroll
      for (int i = 0; i < 4; ++i)
        #pragma unroll
        for (int j = 0; j < 4; ++j) acc[i][j] += a[i] * b[j];
    }
    __syncthreads();
  }
  #pragma unroll
  for (int i = 0; i < 4; ++i)
    #pragma unroll
    for (int j = 0; j < 4; ++j)
      S[(size_t)(bi + ty * 4 + i) * NN + bj + tx * 4 + j] = acc[i][j];
}

// ---------------------------------------------------------------- gated: top-50 per row
__global__ __launch_bounds__(256) void k_topk(const float* __restrict__ sim,
                                              float* __restrict__ vals,
                                              int* __restrict__ idxo,
                                              const int* __restrict__ gate) {
  if (gate[0] == 0) return;
  const int row = blockIdx.x, t = threadIdx.x;
  __shared__ float sv[NN];
  __shared__ float bw[4];
  __shared__ int bj4[4];
  const float* sr = sim + (size_t)row * NN;
  for (int j = t; j < NN; j += 256) sv[j] = sr[j];
  __syncthreads();
  for (int it = 0; it < KTOP; ++it) {
    float bv = -3.4e38f; int bj = NN;
    for (int j = t; j < NN; j += 256) {
      const float v = sv[j];
      if (v > bv || (v == bv && j < bj)) { bv = v; bj = j; }
    }
    #pragma unroll
    for (int o = 32; o; o >>= 1) {
      const float ov = __shfl_down(bv, o);
      const int oj = __shfl_down(bj, o);
      if (ov > bv || (ov == bv && oj < bj)) { bv = ov; bj = oj; }
    }
    if ((t & 63) == 0) { bw[t >> 6] = bv; bj4[t >> 6] = bj; }
    __syncthreads();
    if (t == 0) {
      #pragma unroll
      for (int q = 1; q < 4; ++q)
        if (bw[q] > bv || (bw[q] == bv && bj4[q] < bj)) { bv = bw[q]; bj = bj4[q]; }
      vals[row * KTOP + it] = bv;
      idxo[row * KTOP + it] = bj;
      sv[bj] = -3.4e38f;
    }
    __syncthreads();
  }
}

// ---------------------------------------------------------------- gated: zero A_new region (grid-stride)
__global__ __launch_bounds__(256) void k_zero(float* __restrict__ p, const int* __restrict__ gate) {
  if (gate[0] == 0) return;
  const size_t stride = (size_t)gridDim.x * 256;
  for (size_t i = (size_t)blockIdx.x * 256 + threadIdx.x; i < (size_t)NN * NN / 4; i += stride)
    ((f32x4*)p)[i] = f32x4{0.f, 0.f, 0.f, 0.f};
}

// ---------------------------------------------------------------- gated: scatter-symmetrize
__global__ __launch_bounds__(256) void k_scatter(const float* __restrict__ vals,
                                                 const int* __restrict__ idx,
                                                 float* __restrict__ anew,
                                                 const int* __restrict__ gate) {
  if (gate[0] == 0) return;
  const int tid = blockIdx.x * 256 + threadIdx.x;
  if (tid >= NN * KTOP) return;
  const int i = tid / KTOP;
  const float v = vals[tid] * 0.5f;
  const int j = idx[tid];
  atomicAdd(anew + (size_t)i * NN + j, v);
  atomicAdd(anew + (size_t)j * NN + i, v);
}

// ---------------------------------------------------------------- mask + fuse + row sums + bf16 sidecar (always)
__device__ __forceinline__ float maskval(float a, float ev, float di, float m0) {
  if (a > 0.0f) {
    const float w = 2.0f / (1.0f + expf(di - ev));
    return (w >= 1.0f) ? a * w : 0.0f;
  }
  return a * m0;
}

__global__ __launch_bounds__(256) void k_mask_final(float* __restrict__ anew,
                                                    const float* __restrict__ adj,
                                                    const float* __restrict__ e,
                                                    const float* __restrict__ delta,
                                                    float* __restrict__ afin,
                                                    ushort* __restrict__ afb,
                                                    float* __restrict__ dinv2f,
                                                    const int* __restrict__ gate) {
  const int row = blockIdx.x, t = threadIdx.x;
  const bool fl = gate[0] != 0;
  const float di = delta[row];
  const float w0 = 2.0f / (1.0f + expf(di));
  const float m0 = (w0 >= 1.0f) ? w0 : 0.0f;
  const f32x4* ar = (const f32x4*)(adj + (size_t)row * NN);
  f32x4* an = (f32x4*)(anew + (size_t)row * NN);
  f32x4* af = (f32x4*)(afin + (size_t)row * NN);
  ushort* ab = afb + (size_t)row * NN;
  const f32x4* ef = (const f32x4*)e;
  float s = 0.f;
  for (int q = t; q < NN / 4; q += 256) {
    f32x4 a = fl ? an[q] : f32x4{0.f, 0.f, 0.f, 0.f};
    const f32x4 ad = ar[q];
    const f32x4 ev = ef[q];
    f32x4 ao, fo;
    ao.x = maskval(a.x, ev.x, di, m0); fo.x = ao.x + ad.x;
    ao.y = maskval(a.y, ev.y, di, m0); fo.y = ao.y + ad.y;
    ao.z = maskval(a.z, ev.z, di, m0); fo.z = ao.z + ad.z;
    ao.w = maskval(a.w, ev.w, di, m0); fo.w = ao.w + ad.w;
    s += fo.x + fo.y + fo.z + fo.w;
    __builtin_nontemporal_store(ao, an + q);
    __builtin_nontemporal_store(fo, af + q);
    u16x4 hb;
    hb.x = f2b(fo.x); hb.y = f2b(fo.y); hb.z = f2b(fo.z); hb.w = f2b(fo.w);
    *(u16x4*)(ab + q * 4) = hb;
  }
  s = wave_sum(s);
  __shared__ float sm[4];
  if ((t & 63) == 0) sm[t >> 6] = s;
  __syncthreads();
  if (t == 0) {
    const float tot = sm[0] + sm[1] + sm[2] + sm[3];
    dinv2f[row] = tot > 0.f ? 1.0f / sqrtf(tot) : 0.0f;
  }
}

// ---------------------------------------------------------------- launcher
extern "C" void kernel_launch(void* const* d_in, const int* in_sizes, int n_in,
                              void* d_out, int out_size, void* d_ws, size_t ws_size,
                              hipStream_t stream) {
  const float* input = (const float*)d_in[0];
  const float* Adj   = (const float*)d_in[1];
  const float* unc   = (const float*)d_in[2];
  const float* w1    = (const float*)d_in[3];
  const float* w2    = (const float*)d_in[4];
  const float* delta = (const float*)d_in[5];
  const float* W1    = (const float*)d_in[6];
  const float* b1    = (const float*)d_in[7];
  const float* W2    = (const float*)d_in[8];
  const float* b2    = (const float*)d_in[9];

  float* xout = (float*)d_out;
  float* anew = xout + (size_t)NN * CCC;
  float* afin = anew + (size_t)NN * NN;

  float* w = (float*)d_ws;
  size_t o = 0;
  float* DINV  = w + o; o += NN;
  float* DSQ   = w + o; o += NN;
  float* EARR  = w + o; o += NN;
  float* DINV2 = w + o; o += NN;
  int*   FLAG  = (int*)(w + o); o += NN;
  // union region: gated scratch chain OR bf16 A_final sidecar (written after chain is dead)
  float* REGION = w + o; o += (size_t)NN * NN / 2;          // 18.87M floats = NN*NN ushorts
  float* X1   = REGION;
  float* X2   = X1 + (size_t)NN * FF;
  float* EMBP = X2 + (size_t)NN * FF;
  float* EMBN = EMBP + (size_t)NN * FF;
  float* VALS = EMBN + (size_t)NN * FF;
  int*   IDX  = (int*)(VALS + (size_t)NN * KTOP);
  ushort* AFINB = (ushort*)REGION;
  float* Y1    = w + o; o += (size_t)NN * HH;
  float* XRELU = w + o; o += (size_t)NN * HH;
  float* Y2    = w + o; o += (size_t)NN * CCC;
  ushort* Y1T  = (ushort*)(w + o); o += (size_t)NN * HH / 2;
  ushort* Y2T  = (ushort*)(w + o); o += (size_t)NN * CCC / 2;
  float* PK    = w + o; o += (size_t)4 * NN * HH;           // split-K partials

  // 1. gate + e = exp(-u)
  k_flag<<<1, 256, 0, stream>>>(unc, delta, EARR, FLAG);
  // 2. degrees of Adj (gated: only the dead chain consumes them)
  k_rowsum<<<NN, 256, 0, stream>>>(Adj, DINV, DSQ, FLAG);

  // ---- gated graph-revision chain (dead unless some exp(-u_j) >= min delta) ----
  k_prescale<<<(NN * FF / 4) / 256, 256, 0, stream>>>(input, DINV, w1, X1, FLAG);
  k_gemm<128, 2, true, false><<<dim3(96, 4, 1), 256, 0, stream>>>(Adj, X1, X2, DSQ, w2, nullptr, NN, NN, FF, FLAG);
  k_gemm<128, 0, true, false><<<dim3(96, 4, 1), 256, 0, stream>>>(Adj, X2, EMBP, nullptr, nullptr, nullptr, NN, NN, FF, FLAG);
  k_normalize<<<NN, 256, 0, stream>>>(EMBP, DINV, EMBN, FLAG);
  k_sim<<<dim3(96, 96, 1), 256, 0, stream>>>(EMBN, afin, FLAG);            // sim scratch in A_final region
  k_topk<<<NN, 256, 0, stream>>>(afin, VALS, IDX, FLAG);
  k_zero<<<2048, 256, 0, stream>>>(anew, FLAG);
  k_scatter<<<(NN * KTOP + 255) / 256, 256, 0, stream>>>(VALS, IDX, anew, FLAG);

  // ---- mask, fuse with Adj, row sums of A_final, bf16 sidecar (always) ----
  k_mask_final<<<NN, 256, 0, stream>>>(anew, Adj, EARR, delta, afin, AFINB, DINV2, FLAG);

  // ---- task GCN with D^-1/2 folded ----
  // Y1 = dinv2 (.) (input @ W1), also emit Y1T bf16
  k_gemm<128, 0, false, true><<<dim3(96, 1, 4), 256, 0, stream>>>(input, W1, PK, nullptr, nullptr, nullptr, NN, FF, HH, nullptr);
  k_reduce<1><<<(NN * HH) / 256, 256, 0, stream>>>(PK, Y1, DINV2, nullptr, nullptr, NN, HH, 4, Y1T);
  // XRELU = relu(dinv2 (.) (A_final @ Y1) + b1)   [MFMA bf16, split-K=4]
  k_mfma<128, 4><<<dim3(96, 1, 4), 256, 0, stream>>>(AFINB, Y1T, PK);
  k_reduce<3><<<(NN * HH) / 256, 256, 0, stream>>>(PK, XRELU, DINV2, nullptr, b1, NN, HH, 4, nullptr);
  // Y2 = dinv2 (.) (XRELU @ W2), also emit Y2T bf16
  k_gemm<16, 0, false, true><<<dim3(96, 1, 1), 256, 0, stream>>>(XRELU, W2, PK, nullptr, nullptr, nullptr, NN, HH, CCC, nullptr);
  k_reduce<1><<<(NN * CCC) / 256, 256, 0, stream>>>(PK, Y2, DINV2, nullptr, nullptr, NN, CCC, 1, Y2T);
  // x = dinv2 (.) (A_final @ Y2) + b2   [MFMA bf16, split-K=8]
  k_mfma<16, 8><<<dim3(96, 1, 8), 256, 0, stream>>>(AFINB, Y2T, PK);
  k_reduce<4><<<(NN * CCC) / 256, 256, 0, stream>>>(PK, xout, DINV2, nullptr, b2, NN, CCC, 8, nullptr);
}

// Round 4
// 273.396 us; speedup vs baseline: 1.5119x; 1.0821x over previous
//
#include <hip/hip_runtime.h>
#include <cstddef>
#include <cstdint>

#define NN 6144
#define FF 512
#define HH 128
#define CCC 16
#define KTOP 50

typedef __attribute__((ext_vector_type(8))) short bf16x8;
typedef __attribute__((ext_vector_type(4))) float f32x4;
typedef __attribute__((ext_vector_type(4))) ushort u16x4;

// ---------------------------------------------------------------- helpers
__device__ __forceinline__ float wave_sum(float v) {
  #pragma unroll
  for (int o = 32; o; o >>= 1) v += __shfl_down(v, o);
  return v;
}

__device__ __forceinline__ ushort f2b(float x) {   // fp32 -> bf16 RNE
  union { float f; uint32_t u; } v; v.f = x;
  const uint32_t r = v.u + 0x7FFFu + ((v.u >> 16) & 1u);
  return (ushort)(r >> 16);
}

// ---------------------------------------------------------------- gate + e[] = exp(-u)
__global__ __launch_bounds__(256) void k_flag(const float* __restrict__ u,
                                              const float* __restrict__ delta,
                                              float* __restrict__ e,
                                              int* __restrict__ flag) {
  const int t = threadIdx.x;
  float emax = -1e30f, dmin = 1e30f;
  for (int j = t; j < NN; j += 256) {
    float ev = expf(-u[j]);
    e[j] = ev;
    emax = fmaxf(emax, ev);
    dmin = fminf(dmin, delta[j]);
  }
  #pragma unroll
  for (int o = 32; o; o >>= 1) {
    emax = fmaxf(emax, __shfl_down(emax, o));
    dmin = fminf(dmin, __shfl_down(dmin, o));
  }
  __shared__ float sm[4], sn[4];
  if ((t & 63) == 0) { sm[t >> 6] = emax; sn[t >> 6] = dmin; }
  __syncthreads();
  if (t == 0) {
    emax = fmaxf(fmaxf(sm[0], sm[1]), fmaxf(sm[2], sm[3]));
    dmin = fminf(fminf(sn[0], sn[1]), fminf(sn[2], sn[3]));
    flag[0] = (emax >= dmin || dmin <= 0.0f) ? 1 : 0;
  }
}

// ---------------------------------------------------------------- weight transposes to bf16 (always)
__global__ __launch_bounds__(256) void k_prep(const float* __restrict__ W1,
                                              const float* __restrict__ W2,
                                              ushort* __restrict__ W1T,
                                              ushort* __restrict__ W2T) {
  const int idx = blockIdx.x * 256 + threadIdx.x;
  if (idx < FF * HH) {            // W1T[c][r] = W1[r][c]
    const int rr = idx >> 7, cc = idx & 127;
    W1T[(size_t)cc * FF + rr] = f2b(W1[idx]);
  }
  if (idx < HH * CCC) {           // W2T[c][r] = W2[r][c]
    const int rr = idx >> 4, cc = idx & 15;
    W2T[(size_t)cc * HH + rr] = f2b(W2[idx]);
  }
}

// ---------------------------------------------------------------- gated: row sums of Adj (row-loop)
__global__ __launch_bounds__(256) void k_rowsum(const float* __restrict__ A,
                                                float* __restrict__ dinv,
                                                float* __restrict__ dsq,
                                                const int* __restrict__ gate) {
  if (gate[0] == 0) return;
  const int t = threadIdx.x;
  __shared__ float sm[4];
  for (int row = blockIdx.x; row < NN; row += gridDim.x) {
    const float4* Ar = (const float4*)(A + (size_t)row * NN);
    float s = 0.f;
    for (int j = t; j < NN / 4; j += 256) {
      float4 v = Ar[j];
      s += v.x + v.y + v.z + v.w;
    }
    s = wave_sum(s);
    if ((t & 63) == 0) sm[t >> 6] = s;
    __syncthreads();
    if (t == 0) {
      float tot = sm[0] + sm[1] + sm[2] + sm[3];
      float dv = tot > 0.f ? 1.0f / sqrtf(tot) : 0.0f;
      dinv[row] = dv;
      dsq[row] = dv * dv;
    }
    __syncthreads();
  }
}

// ---------------------------------------------------------------- gated: X1 = dinv (.) input (.) w1
__global__ __launch_bounds__(256) void k_prescale(const float* __restrict__ in,
                                                  const float* __restrict__ dinv,
                                                  const float* __restrict__ w1,
                                                  float* __restrict__ X1,
                                                  const int* __restrict__ gate) {
  if (gate[0] == 0) return;
  const int stride = gridDim.x * 256;
  for (int idx = blockIdx.x * 256 + threadIdx.x; idx < NN * FF / 4; idx += stride) {
    const int f4 = idx % (FF / 4), i = idx / (FF / 4);
    float4 v = ((const float4*)in)[idx];
    float4 w = ((const float4*)w1)[f4];
    const float d = dinv[i];
    v.x *= d * w.x; v.y *= d * w.y; v.z *= d * w.z; v.w *= d * w.w;
    ((float4*)X1)[idx] = v;
  }
}

// ---------------------------------------------------------------- epilogue helper
template <int MODE>
__device__ __forceinline__ float epi(float v, int r, int c,
                                     const float* rs, const float* cs, const float* bias) {
  if constexpr (MODE == 1) return v * rs[r];
  if constexpr (MODE == 2) return v * rs[r] * cs[c];
  if constexpr (MODE == 3) { float o = v * rs[r] + bias[c]; return o > 0.f ? o : 0.f; }
  if constexpr (MODE == 4) return v * rs[r] + bias[c];
  return v;
}

// ---------------------------------------------------------------- gated fp32 GEMM  C = A @ X  (graph-revision only)
template <int BN, int MODE>
__global__ __launch_bounds__(256) void k_gemm(const float* __restrict__ A,
                                              const float* __restrict__ X,
                                              float* __restrict__ C,
                                              const float* __restrict__ rs,
                                              const float* __restrict__ cs,
                                              int M, int K, int NC,
                                              const int* __restrict__ gate) {
  if (gate[0] == 0) return;
  constexpr int BM = 64, BK = 32;
  constexpr int TN = 8;
  const int row0 = blockIdx.x * BM;
  const int col0 = blockIdx.y * BN;
  __shared__ float As[BM][BK + 1];
  __shared__ float Xs[BK][BN];
  const int t = threadIdx.x;
  const int tx = t & 15, ty = t >> 4;
  float acc[4][TN];
  #pragma unroll
  for (int i = 0; i < 4; ++i)
    #pragma unroll
    for (int j = 0; j < TN; ++j) acc[i][j] = 0.f;

  for (int k0 = 0; k0 < K; k0 += BK) {
    #pragma unroll
    for (int s = t; s < BM * BK / 4; s += 256) {
      const int r = s >> 3, q = s & 7;
      float4 v = *(const float4*)(A + (size_t)(row0 + r) * K + k0 + q * 4);
      As[r][q * 4 + 0] = v.x; As[r][q * 4 + 1] = v.y;
      As[r][q * 4 + 2] = v.z; As[r][q * 4 + 3] = v.w;
    }
    for (int s = t; s < BK * BN / 4; s += 256) {
      const int r = s / (BN / 4), q = s % (BN / 4);
      *(float4*)&Xs[r][q * 4] = *(const float4*)(X + (size_t)(k0 + r) * NC + col0 + q * 4);
    }
    __syncthreads();
    #pragma unroll
    for (int kk = 0; kk < BK; ++kk) {
      float a[4];
      #pragma unroll
      for (int i = 0; i < 4; ++i) a[i] = As[ty * 4 + i][kk];
      float4 x0 = *(float4*)&Xs[kk][tx * 8];
      float4 x1 = *(float4*)&Xs[kk][tx * 8 + 4];
      #pragma unroll
      for (int i = 0; i < 4; ++i) {
        acc[i][0] += a[i] * x0.x; acc[i][1] += a[i] * x0.y;
        acc[i][2] += a[i] * x0.z; acc[i][3] += a[i] * x0.w;
        acc[i][4] += a[i] * x1.x; acc[i][5] += a[i] * x1.y;
        acc[i][6] += a[i] * x1.z; acc[i][7] += a[i] * x1.w;
      }
    }
    __syncthreads();
  }
  #pragma unroll
  for (int i = 0; i < 4; ++i)
    #pragma unroll
    for (int j = 0; j < TN; ++j) {
      const int r = row0 + ty * 4 + i, c = col0 + tx * TN + j;
      C[(size_t)r * NC + c] = epi<MODE>(acc[i][j], r, c, rs, cs, nullptr);
    }
}

// ---------------------------------------------------------------- split-K reduce + epilogue + bf16 emit
// EMIT: 0 none, 1 transposed [NC][M], 2 row-major [M][NC]
template <int MODE, int EMIT>
__global__ __launch_bounds__(256) void k_reduce(const float* __restrict__ P,
                                                float* __restrict__ C,
                                                const float* __restrict__ rs,
                                                const float* __restrict__ bias,
                                                int M, int NC, int S,
                                                ushort* __restrict__ bt) {
  const size_t idx = (size_t)blockIdx.x * 256 + threadIdx.x;
  const size_t tot = (size_t)M * NC;
  float s = 0.f;
  for (int p = 0; p < S; ++p) s += P[p * tot + idx];
  const int r = (int)(idx / NC), c = (int)(idx % NC);
  const float v = epi<MODE>(s, r, c, rs, nullptr, bias);
  if (C) C[idx] = v;
  if constexpr (EMIT == 1) bt[(size_t)c * M + r] = f2b(v);
  if constexpr (EMIT == 2) bt[idx] = f2b(v);
}

// ---------------------------------------------------------------- MFMA bf16 GEMM: P[z] = A[M=6144][K] @ BT^T
template <int NC, int SPLITS>
__global__ __launch_bounds__(256) void k_mfma(const ushort* __restrict__ A,
                                              const ushort* __restrict__ BT,
                                              float* __restrict__ P, int K) {
  const int wave = threadIdx.x >> 6, lane = threadIdx.x & 63;
  const int m0 = blockIdx.x * 64 + wave * 16;
  const int klen = K / SPLITS;
  const int kbeg = blockIdx.z * klen;
  const int r = lane & 15, kg = lane >> 4;
  constexpr int NB = NC / 16;
  f32x4 acc[NB];
  #pragma unroll
  for (int i = 0; i < NB; ++i) acc[i] = f32x4{0.f, 0.f, 0.f, 0.f};
  const ushort* a_ptr = A + (size_t)(m0 + r) * K + kbeg + kg * 8;
  const ushort* b_ptr = BT + (size_t)r * K + kbeg + kg * 8;
  #pragma unroll 4
  for (int k = 0; k < klen; k += 32) {
    const bf16x8 av = *(const bf16x8*)(a_ptr + k);
    #pragma unroll
    for (int nb = 0; nb < NB; ++nb) {
      const bf16x8 bv = *(const bf16x8*)(b_ptr + (size_t)nb * 16 * K + k);
      acc[nb] = __builtin_amdgcn_mfma_f32_16x16x32_bf16(av, bv, acc[nb], 0, 0, 0);
    }
  }
  float* Pz = P + (size_t)blockIdx.z * NN * NC;
  #pragma unroll
  for (int nb = 0; nb < NB; ++nb)
    #pragma unroll
    for (int i = 0; i < 4; ++i)
      Pz[(size_t)(m0 + kg * 4 + i) * NC + nb * 16 + r] = acc[nb][i];
}

// ---------------------------------------------------------------- MFMA with fp32 A (converted to bf16 in-flight)
template <int NC, int SPLITS>
__global__ __launch_bounds__(256) void k_mfma_f32a(const float* __restrict__ A,
                                                   const ushort* __restrict__ BT,
                                                   float* __restrict__ P, int K) {
  const int wave = threadIdx.x >> 6, lane = threadIdx.x & 63;
  const int m0 = blockIdx.x * 64 + wave * 16;
  const int klen = K / SPLITS;
  const int kbeg = blockIdx.z * klen;
  const int r = lane & 15, kg = lane >> 4;
  constexpr int NB = NC / 16;
  f32x4 acc[NB];
  #pragma unroll
  for (int i = 0; i < NB; ++i) acc[i] = f32x4{0.f, 0.f, 0.f, 0.f};
  const float* a_ptr = A + (size_t)(m0 + r) * K + kbeg + kg * 8;
  const ushort* b_ptr = BT + (size_t)r * K + kbeg + kg * 8;
  for (int k = 0; k < klen; k += 32) {
    const float4 f0 = *(const float4*)(a_ptr + k);
    const float4 f1 = *(const float4*)(a_ptr + k + 4);
    bf16x8 av;
    av[0] = (short)f2b(f0.x); av[1] = (short)f2b(f0.y);
    av[2] = (short)f2b(f0.z); av[3] = (short)f2b(f0.w);
    av[4] = (short)f2b(f1.x); av[5] = (short)f2b(f1.y);
    av[6] = (short)f2b(f1.z); av[7] = (short)f2b(f1.w);
    #pragma unroll
    for (int nb = 0; nb < NB; ++nb) {
      const bf16x8 bv = *(const bf16x8*)(b_ptr + (size_t)nb * 16 * K + k);
      acc[nb] = __builtin_amdgcn_mfma_f32_16x16x32_bf16(av, bv, acc[nb], 0, 0, 0);
    }
  }
  float* Pz = P + (size_t)blockIdx.z * NN * NC;
  #pragma unroll
  for (int nb = 0; nb < NB; ++nb)
    #pragma unroll
    for (int i = 0; i < 4; ++i)
      Pz[(size_t)(m0 + kg * 4 + i) * NC + nb * 16 + r] = acc[nb][i];
}

// ---------------------------------------------------------------- gated: row-normalize embeddings (row-loop)
__global__ __launch_bounds__(256) void k_normalize(const float* __restrict__ embp,
                                                   const float* __restrict__ dinv,
                                                   float* __restrict__ embn,
                                                   const int* __restrict__ gate) {
  if (gate[0] == 0) return;
  const int t = threadIdx.x;
  __shared__ float sm[4];
  __shared__ float inv_s;
  for (int row = blockIdx.x; row < NN; row += gridDim.x) {
    const float d = dinv[row];
    const float v0 = embp[(size_t)row * FF + t] * d;
    const float v1 = embp[(size_t)row * FF + 256 + t] * d;
    float ss = wave_sum(v0 * v0 + v1 * v1);
    if ((t & 63) == 0) sm[t >> 6] = ss;
    __syncthreads();
    if (t == 0) {
      const float nrm = sqrtf(sm[0] + sm[1] + sm[2] + sm[3]);
      inv_s = 1.0f / fmaxf(nrm, 1e-12f);
    }
    __syncthreads();
    const float inv = inv_s;
    embn[(size_t)row * FF + t] = v0 * inv;
    embn[(size_t)row * FF + 256 + t] = v1 * inv;
    __syncthreads();
  }
}

// ---------------------------------------------------------------- gated: sim = U @ U^T (tile-loop)
__global__ __launch_bounds__(256) void k_sim(const float* __restrict__ U,
                                             float* __restrict__ S,
                                             const int* __restrict__ gate) {
  if (gate[0] == 0) return;
  __shared__ float Ui[64][33], Uj[64][33];
  const int t = threadIdx.x, tx = t & 15, ty = t >> 4;
  for (int tile = blockIdx.x; tile < 96 * 96; tile += gridDim.x) {
    const int bi = (tile / 96) * 64, bj = (tile % 96) * 64;
    float acc[4][4];
    #pragma unroll
    for (int i = 0; i < 4; ++i)
      #pragma unroll
      for (int j = 0; j < 4; ++j) acc[i][j] = 0.f;
    for (int k0 = 0; k0 < FF; k0 += 32) {
      #pragma unroll
      for (int s = t; s < 512; s += 256) {
        const int r = s >> 3, q = s & 7;
        float4 v = *(const float4*)(U + (size_t)(bi + r) * FF + k0 + q * 4);
        Ui[r][q * 4 + 0] = v.x; Ui[r][q * 4 + 1] = v.y; Ui[r][q * 4 + 2] = v.z; Ui[r][q * 4 + 3] = v.w;
        float4 w = *(const float4*)(U + (size_t)(bj + r) * FF + k0 + q * 4);
        Uj[r][q * 4 + 0] = w.x; Uj[r][q * 4 + 1] = w.y; Uj[r][q * 4 + 2] = w.z; Uj[r][q * 4 + 3] = w.w;
      }
      __syncthreads();
      #pragma unroll
      for (int kk = 0; kk < 32; ++kk) {
        float a[4], b[4];
        #pragma unroll
        for (int i = 0; i < 4; ++i) a[i] = Ui[ty * 4 + i][kk];
        #pragma unroll
        for (int j = 0; j < 4; ++j) b[j] = Uj[tx * 4 + j][kk];
        #pragma unroll
        for (int i = 0; i < 4; ++i)
          #pragma unroll
          for (int j = 0; j < 4; ++j) acc[i][j] += a[i] * b[j];
      }
      __syncthreads();
    }
    #pragma unroll
    for (int i = 0; i < 4; ++i)
      #pragma unroll
      for (int j = 0; j < 4; ++j)
        S[(size_t)(bi + ty * 4 + i) * NN + bj + tx * 4 + j] = acc[i][j];
  }
}

// ---------------------------------------------------------------- gated: top-50 per row (row-loop)
__global__ __launch_bounds__(256) void k_topk(const float* __restrict__ sim,
                                              float* __restrict__ vals,
                                              int* __restrict__ idxo,
                                              const int* __restrict__ gate) {
  if (gate[0] == 0) return;
  const int t = threadIdx.x;
  __shared__ float sv[NN];
  __shared__ float bw[4];
  __shared__ int bj4[4];
  for (int row = blockIdx.x; row < NN; row += gridDim.x) {
    const float* sr = sim + (size_t)row * NN;
    for (int j = t; j < NN; j += 256) sv[j] = sr[j];
    __syncthreads();
    for (int it = 0; it < KTOP; ++it) {
      float bv = -3.4e38f; int bj = NN;
      for (int j = t; j < NN; j += 256) {
        const float v = sv[j];
        if (v > bv || (v == bv && j < bj)) { bv = v; bj = j; }
      }
      #pragma unroll
      for (int o = 32; o; o >>= 1) {
        const float ov = __shfl_down(bv, o);
        const int oj = __shfl_down(bj, o);
        if (ov > bv || (ov == bv && oj < bj)) { bv = ov; bj = oj; }
      }
      if ((t & 63) == 0) { bw[t >> 6] = bv; bj4[t >> 6] = bj; }
      __syncthreads();
      if (t == 0) {
        #pragma unroll
        for (int q = 1; q < 4; ++q)
          if (bw[q] > bv || (bw[q] == bv && bj4[q] < bj)) { bv = bw[q]; bj = bj4[q]; }
        vals[row * KTOP + it] = bv;
        idxo[row * KTOP + it] = bj;
        sv[bj] = -3.4e38f;
      }
      __syncthreads();
    }
  }
}

// ---------------------------------------------------------------- gated: zero A_new region (grid-stride)
__global__ __launch_bounds__(256) void k_zero(float* __restrict__ p, const int* __restrict__ gate) {
  if (gate[0] == 0) return;
  const size_t stride = (size_t)gridDim.x * 256;
  for (size_t i = (size_t)blockIdx.x * 256 + threadIdx.x; i < (size_t)NN * NN / 4; i += stride)
    ((f32x4*)p)[i] = f32x4{0.f, 0.f, 0.f, 0.f};
}

// ---------------------------------------------------------------- gated: scatter-symmetrize (grid-stride)
__global__ __launch_bounds__(256) void k_scatter(const float* __restrict__ vals,
                                                 const int* __restrict__ idx,
                                                 float* __restrict__ anew,
                                                 const int* __restrict__ gate) {
  if (gate[0] == 0) return;
  const int stride = gridDim.x * 256;
  for (int tid = blockIdx.x * 256 + threadIdx.x; tid < NN * KTOP; tid += stride) {
    const int i = tid / KTOP;
    const float v = vals[tid] * 0.5f;
    const int j = idx[tid];
    atomicAdd(anew + (size_t)i * NN + j, v);
    atomicAdd(anew + (size_t)j * NN + i, v);
  }
}

// ---------------------------------------------------------------- mask + fuse + row sums + bf16 sidecar (always)
__device__ __forceinline__ float maskval(float a, float ev, float di, float m0) {
  if (a > 0.0f) {
    const float w = 2.0f / (1.0f + expf(di - ev));
    return (w >= 1.0f) ? a * w : 0.0f;
  }
  return a * m0;
}

__global__ __launch_bounds__(256) void k_mask_final(float* __restrict__ anew,
                                                    const float* __restrict__ adj,
                                                    const float* __restrict__ e,
                                                    const float* __restrict__ delta,
                                                    float* __restrict__ afin,
                                                    ushort* __restrict__ afb,
                                                    float* __restrict__ dinv2f,
                                                    const int* __restrict__ gate) {
  const int row = blockIdx.x, t = threadIdx.x;
  const bool fl = gate[0] != 0;
  const float di = delta[row];
  const float w0 = 2.0f / (1.0f + expf(di));
  const float m0 = (w0 >= 1.0f) ? w0 : 0.0f;
  const f32x4* ar = (const f32x4*)(adj + (size_t)row * NN);
  f32x4* an = (f32x4*)(anew + (size_t)row * NN);
  f32x4* af = (f32x4*)(afin + (size_t)row * NN);
  ushort* ab = afb + (size_t)row * NN;
  const f32x4* ef = (const f32x4*)e;
  float s = 0.f;
  for (int q = t; q < NN / 4; q += 256) {
    f32x4 a = fl ? an[q] : f32x4{0.f, 0.f, 0.f, 0.f};
    const f32x4 ad = ar[q];
    const f32x4 ev = ef[q];
    f32x4 ao, fo;
    ao.x = maskval(a.x, ev.x, di, m0); fo.x = ao.x + ad.x;
    ao.y = maskval(a.y, ev.y, di, m0); fo.y = ao.y + ad.y;
    ao.z = maskval(a.z, ev.z, di, m0); fo.z = ao.z + ad.z;
    ao.w = maskval(a.w, ev.w, di, m0); fo.w = ao.w + ad.w;
    s += fo.x + fo.y + fo.z + fo.w;
    __builtin_nontemporal_store(ao, an + q);
    __builtin_nontemporal_store(fo, af + q);
    u16x4 hb;
    hb.x = f2b(fo.x); hb.y = f2b(fo.y); hb.z = f2b(fo.z); hb.w = f2b(fo.w);
    *(u16x4*)(ab + q * 4) = hb;
  }
  s = wave_sum(s);
  __shared__ float sm[4];
  if ((t & 63) == 0) sm[t >> 6] = s;
  __syncthreads();
  if (t == 0) {
    const float tot = sm[0] + sm[1] + sm[2] + sm[3];
    dinv2f[row] = tot > 0.f ? 1.0f / sqrtf(tot) : 0.0f;
  }
}

// ---------------------------------------------------------------- launcher
extern "C" void kernel_launch(void* const* d_in, const int* in_sizes, int n_in,
                              void* d_out, int out_size, void* d_ws, size_t ws_size,
                              hipStream_t stream) {
  const float* input = (const float*)d_in[0];
  const float* Adj   = (const float*)d_in[1];
  const float* unc   = (const float*)d_in[2];
  const float* w1    = (const float*)d_in[3];
  const float* w2    = (const float*)d_in[4];
  const float* delta = (const float*)d_in[5];
  const float* W1    = (const float*)d_in[6];
  const float* b1    = (const float*)d_in[7];
  const float* W2    = (const float*)d_in[8];
  const float* b2    = (const float*)d_in[9];

  float* xout = (float*)d_out;
  float* anew = xout + (size_t)NN * CCC;
  float* afin = anew + (size_t)NN * NN;

  float* w = (float*)d_ws;
  size_t o = 0;
  float* DINV  = w + o; o += NN;
  float* DSQ   = w + o; o += NN;
  float* EARR  = w + o; o += NN;
  float* DINV2 = w + o; o += NN;
  int*   FLAG  = (int*)(w + o); o += NN;
  // union region: gated scratch chain OR bf16 A_final sidecar (chain is dead by then)
  float* REGION = w + o; o += (size_t)NN * NN / 2;          // NN*NN ushorts
  float* X1   = REGION;
  float* X2   = X1 + (size_t)NN * FF;
  float* EMBP = X2 + (size_t)NN * FF;
  float* EMBN = EMBP + (size_t)NN * FF;
  float* VALS = EMBN + (size_t)NN * FF;
  int*   IDX  = (int*)(VALS + (size_t)NN * KTOP);
  ushort* AFINB = (ushort*)REGION;
  ushort* Y1T    = (ushort*)(w + o); o += (size_t)NN * HH / 2;    // [128][6144]
  ushort* XRELUB = (ushort*)(w + o); o += (size_t)NN * HH / 2;    // [6144][128]
  ushort* Y2T    = (ushort*)(w + o); o += (size_t)NN * CCC / 2;   // [16][6144]
  ushort* W1T    = (ushort*)(w + o); o += (size_t)FF * HH / 2;    // [128][512]
  ushort* W2T    = (ushort*)(w + o); o += (size_t)HH * CCC / 2 + 64;
  float* PK      = w + o; o += (size_t)4 * NN * HH;               // split-K partials (12.6 MB)

  // gate + e = exp(-u); weight transposes
  k_flag<<<1, 256, 0, stream>>>(unc, delta, EARR, FLAG);
  k_prep<<<(FF * HH + 255) / 256, 256, 0, stream>>>(W1, W2, W1T, W2T);

  // ---- gated graph-revision chain (dead unless some exp(-u_j) >= min delta) ----
  k_rowsum<<<512, 256, 0, stream>>>(Adj, DINV, DSQ, FLAG);
  k_prescale<<<1024, 256, 0, stream>>>(input, DINV, w1, X1, FLAG);
  k_gemm<128, 2><<<dim3(96, 4, 1), 256, 0, stream>>>(Adj, X1, X2, DSQ, w2, NN, NN, FF, FLAG);
  k_gemm<128, 0><<<dim3(96, 4, 1), 256, 0, stream>>>(Adj, X2, EMBP, nullptr, nullptr, NN, NN, FF, FLAG);
  k_normalize<<<1024, 256, 0, stream>>>(EMBP, DINV, EMBN, FLAG);
  k_sim<<<1024, 256, 0, stream>>>(EMBN, afin, FLAG);              // sim scratch in A_final region
  k_topk<<<512, 256, 0, stream>>>(afin, VALS, IDX, FLAG);
  k_zero<<<1024, 256, 0, stream>>>(anew, FLAG);
  k_scatter<<<512, 256, 0, stream>>>(VALS, IDX, anew, FLAG);

  // ---- mask, fuse with Adj, row sums of A_final, bf16 sidecar (always) ----
  k_mask_final<<<NN, 256, 0, stream>>>(anew, Adj, EARR, delta, afin, AFINB, DINV2, FLAG);

  // ---- task GCN, all-MFMA, D^-1/2 folded into operands/epilogues ----
  // Y1T = bf16(dinv2 (.) (input @ W1))^T        [128][6144]
  k_mfma_f32a<128, 4><<<dim3(96, 1, 4), 256, 0, stream>>>(input, W1T, PK, FF);
  k_reduce<1, 1><<<(NN * HH) / 256, 256, 0, stream>>>(PK, nullptr, DINV2, nullptr, NN, HH, 4, Y1T);
  // XRELUB = bf16(relu(dinv2 (.) (A_final @ Y1) + b1))   [6144][128]
  k_mfma<128, 4><<<dim3(96, 1, 4), 256, 0, stream>>>(AFINB, Y1T, PK, NN);
  k_reduce<3, 2><<<(NN * HH) / 256, 256, 0, stream>>>(PK, nullptr, DINV2, b1, NN, HH, 4, XRELUB);
  // Y2T = bf16(dinv2 (.) (XRELU @ W2))^T        [16][6144]
  k_mfma<16, 2><<<dim3(96, 1, 2), 256, 0, stream>>>(XRELUB, W2T, PK, HH);
  k_reduce<1, 1><<<(NN * CCC) / 256, 256, 0, stream>>>(PK, nullptr, DINV2, nullptr, NN, CCC, 2, Y2T);
  // x = dinv2 (.) (A_final @ Y2) + b2
  k_mfma<16, 16><<<dim3(96, 1, 16), 256, 0, stream>>>(AFINB, Y2T, PK, NN);
  k_reduce<4, 0><<<(NN * CCC) / 256, 256, 0, stream>>>(PK, xout, DINV2, b2, NN, CCC, 16, nullptr);
}

// Round 5
// 235.099 us; speedup vs baseline: 1.7582x; 1.1629x over previous
//
#include <hip/hip_runtime.h>
#include <cstddef>
#include <cstdint>

#define NN 6144
#define FF 512
#define HH 128
#define CCC 16
#define KTOP 50

typedef __attribute__((ext_vector_type(8))) short bf16x8;
typedef __attribute__((ext_vector_type(4))) float f32x4;
typedef __attribute__((ext_vector_type(4))) ushort u16x4;

// ---------------------------------------------------------------- helpers
__device__ __forceinline__ float wave_sum(float v) {
  #pragma unroll
  for (int o = 32; o; o >>= 1) v += __shfl_down(v, o);
  return v;
}

__device__ __forceinline__ ushort f2b(float x) {   // fp32 -> bf16 RNE
  union { float f; uint32_t u; } v; v.f = x;
  const uint32_t r = v.u + 0x7FFFu + ((v.u >> 16) & 1u);
  return (ushort)(r >> 16);
}

// ---------------------------------------------------------------- flag + e = exp(-u) + weight transposes (one dispatch)
__global__ __launch_bounds__(256) void k_flag_prep(const float* __restrict__ u,
                                                   const float* __restrict__ delta,
                                                   float* __restrict__ e,
                                                   int* __restrict__ flag,
                                                   const float* __restrict__ W1,
                                                   const float* __restrict__ W2,
                                                   ushort* __restrict__ W1T,
                                                   ushort* __restrict__ W2T) {
  const int b = blockIdx.x, t = threadIdx.x;
  if (b < 256) {                       // weight transposes: FF*HH = 65536 = 256*256
    const int idx = b * 256 + t;
    const int rr = idx >> 7, cc = idx & 127;
    W1T[(size_t)cc * FF + rr] = f2b(W1[idx]);
    if (idx < HH * CCC) {
      const int r2 = idx >> 4, c2 = idx & 15;
      W2T[(size_t)c2 * HH + r2] = f2b(W2[idx]);
    }
    return;
  }
  // flag block
  float emax = -1e30f, dmin = 1e30f;
  for (int j = t; j < NN; j += 256) {
    float ev = expf(-u[j]);
    e[j] = ev;
    emax = fmaxf(emax, ev);
    dmin = fminf(dmin, delta[j]);
  }
  #pragma unroll
  for (int o = 32; o; o >>= 1) {
    emax = fmaxf(emax, __shfl_down(emax, o));
    dmin = fminf(dmin, __shfl_down(dmin, o));
  }
  __shared__ float sm[4], sn[4];
  if ((t & 63) == 0) { sm[t >> 6] = emax; sn[t >> 6] = dmin; }
  __syncthreads();
  if (t == 0) {
    emax = fmaxf(fmaxf(sm[0], sm[1]), fmaxf(sm[2], sm[3]));
    dmin = fminf(fminf(sn[0], sn[1]), fminf(sn[2], sn[3]));
    flag[0] = (emax >= dmin || dmin <= 0.0f) ? 1 : 0;
  }
}

// ---------------------------------------------------------------- gated: row sums of Adj + prescale input (fused, row-loop)
__global__ __launch_bounds__(256) void k_rowsum_prescale(const float* __restrict__ A,
                                                         const float* __restrict__ in,
                                                         const float* __restrict__ w1,
                                                         float* __restrict__ dinv,
                                                         float* __restrict__ dsq,
                                                         float* __restrict__ X1,
                                                         const int* __restrict__ gate) {
  if (gate[0] == 0) return;
  const int t = threadIdx.x;
  __shared__ float sm[4];
  __shared__ float dsh;
  for (int row = blockIdx.x; row < NN; row += gridDim.x) {
    const float4* Ar = (const float4*)(A + (size_t)row * NN);
    float s = 0.f;
    for (int j = t; j < NN / 4; j += 256) {
      float4 v = Ar[j];
      s += v.x + v.y + v.z + v.w;
    }
    s = wave_sum(s);
    if ((t & 63) == 0) sm[t >> 6] = s;
    __syncthreads();
    if (t == 0) {
      float tot = sm[0] + sm[1] + sm[2] + sm[3];
      float dv = tot > 0.f ? 1.0f / sqrtf(tot) : 0.0f;
      dinv[row] = dv;
      dsq[row] = dv * dv;
      dsh = dv;
    }
    __syncthreads();
    const float d = dsh;
    if (t < FF / 4) {
      float4 v = ((const float4*)(in + (size_t)row * FF))[t];
      float4 w = ((const float4*)w1)[t];
      v.x *= d * w.x; v.y *= d * w.y; v.z *= d * w.z; v.w *= d * w.w;
      ((float4*)(X1 + (size_t)row * FF))[t] = v;
    }
    __syncthreads();
  }
}

// ---------------------------------------------------------------- gated fp32 GEMM (tile-loop)  C = A @ X, BN=128
template <int MODE>
__global__ __launch_bounds__(256) void k_gemm(const float* __restrict__ A,
                                              const float* __restrict__ X,
                                              float* __restrict__ C,
                                              const float* __restrict__ rs,
                                              const float* __restrict__ cs,
                                              int M, int K, int NC,
                                              const int* __restrict__ gate) {
  if (gate[0] == 0) return;
  constexpr int BM = 64, BK = 32, BN = 128, TN = 8;
  const int tilesN = NC / BN;
  const int tiles = (M / BM) * tilesN;
  __shared__ float As[BM][BK + 1];
  __shared__ float Xs[BK][BN];
  const int t = threadIdx.x;
  const int tx = t & 15, ty = t >> 4;
  for (int tile = blockIdx.x; tile < tiles; tile += gridDim.x) {
    const int row0 = (tile / tilesN) * BM;
    const int col0 = (tile % tilesN) * BN;
    float acc[4][TN];
    #pragma unroll
    for (int i = 0; i < 4; ++i)
      #pragma unroll
      for (int j = 0; j < TN; ++j) acc[i][j] = 0.f;
    for (int k0 = 0; k0 < K; k0 += BK) {
      #pragma unroll
      for (int s = t; s < BM * BK / 4; s += 256) {
        const int r = s >> 3, q = s & 7;
        float4 v = *(const float4*)(A + (size_t)(row0 + r) * K + k0 + q * 4);
        As[r][q * 4 + 0] = v.x; As[r][q * 4 + 1] = v.y;
        As[r][q * 4 + 2] = v.z; As[r][q * 4 + 3] = v.w;
      }
      for (int s = t; s < BK * BN / 4; s += 256) {
        const int r = s / (BN / 4), q = s % (BN / 4);
        *(float4*)&Xs[r][q * 4] = *(const float4*)(X + (size_t)(k0 + r) * NC + col0 + q * 4);
      }
      __syncthreads();
      #pragma unroll
      for (int kk = 0; kk < BK; ++kk) {
        float a[4];
        #pragma unroll
        for (int i = 0; i < 4; ++i) a[i] = As[ty * 4 + i][kk];
        float4 x0 = *(float4*)&Xs[kk][tx * 8];
        float4 x1 = *(float4*)&Xs[kk][tx * 8 + 4];
        #pragma unroll
        for (int i = 0; i < 4; ++i) {
          acc[i][0] += a[i] * x0.x; acc[i][1] += a[i] * x0.y;
          acc[i][2] += a[i] * x0.z; acc[i][3] += a[i] * x0.w;
          acc[i][4] += a[i] * x1.x; acc[i][5] += a[i] * x1.y;
          acc[i][6] += a[i] * x1.z; acc[i][7] += a[i] * x1.w;
        }
      }
      __syncthreads();
    }
    #pragma unroll
    for (int i = 0; i < 4; ++i)
      #pragma unroll
      for (int j = 0; j < TN; ++j) {
        const int r = row0 + ty * 4 + i, c = col0 + tx * TN + j;
        const float v = acc[i][j];
        float o;
        if constexpr (MODE == 2) o = v * rs[r] * cs[c];
        else o = v;
        C[(size_t)r * NC + c] = o;
      }
  }
}

// ---------------------------------------------------------------- gated: row-normalize embeddings (row-loop)
__global__ __launch_bounds__(256) void k_normalize(const float* __restrict__ embp,
                                                   const float* __restrict__ dinv,
                                                   float* __restrict__ embn,
                                                   const int* __restrict__ gate) {
  if (gate[0] == 0) return;
  const int t = threadIdx.x;
  __shared__ float sm[4];
  __shared__ float inv_s;
  for (int row = blockIdx.x; row < NN; row += gridDim.x) {
    const float d = dinv[row];
    const float v0 = embp[(size_t)row * FF + t] * d;
    const float v1 = embp[(size_t)row * FF + 256 + t] * d;
    float ss = wave_sum(v0 * v0 + v1 * v1);
    if ((t & 63) == 0) sm[t >> 6] = ss;
    __syncthreads();
    if (t == 0) {
      const float nrm = sqrtf(sm[0] + sm[1] + sm[2] + sm[3]);
      inv_s = 1.0f / fmaxf(nrm, 1e-12f);
    }
    __syncthreads();
    const float inv = inv_s;
    embn[(size_t)row * FF + t] = v0 * inv;
    embn[(size_t)row * FF + 256 + t] = v1 * inv;
    __syncthreads();
  }
}

// ---------------------------------------------------------------- gated: sim = U @ U^T (tile-loop)
__global__ __launch_bounds__(256) void k_sim(const float* __restrict__ U,
                                             float* __restrict__ S,
                                             const int* __restrict__ gate) {
  if (gate[0] == 0) return;
  __shared__ float Ui[64][33], Uj[64][33];
  const int t = threadIdx.x, tx = t & 15, ty = t >> 4;
  for (int tile = blockIdx.x; tile < 96 * 96; tile += gridDim.x) {
    const int bi = (tile / 96) * 64, bj = (tile % 96) * 64;
    float acc[4][4];
    #pragma unroll
    for (int i = 0; i < 4; ++i)
      #pragma unroll
      for (int j = 0; j < 4; ++j) acc[i][j] = 0.f;
    for (int k0 = 0; k0 < FF; k0 += 32) {
      #pragma unroll
      for (int s = t; s < 512; s += 256) {
        const int r = s >> 3, q = s & 7;
        float4 v = *(const float4*)(U + (size_t)(bi + r) * FF + k0 + q * 4);
        Ui[r][q * 4 + 0] = v.x; Ui[r][q * 4 + 1] = v.y; Ui[r][q * 4 + 2] = v.z; Ui[r][q * 4 + 3] = v.w;
        float4 w = *(const float4*)(U + (size_t)(bj + r) * FF + k0 + q * 4);
        Uj[r][q * 4 + 0] = w.x; Uj[r][q * 4 + 1] = w.y; Uj[r][q * 4 + 2] = w.z; Uj[r][q * 4 + 3] = w.w;
      }
      __syncthreads();
      #pragma unroll
      for (int kk = 0; kk < 32; ++kk) {
        float a[4], b[4];
        #pragma unroll
        for (int i = 0; i < 4; ++i) a[i] = Ui[ty * 4 + i][kk];
        #pragma unroll
        for (int j = 0; j < 4; ++j) b[j] = Uj[tx * 4 + j][kk];
        #pragma unroll
        for (int i = 0; i < 4; ++i)
          #pragma unroll
          for (int j = 0; j < 4; ++j) acc[i][j] += a[i] * b[j];
      }
      __syncthreads();
    }
    #pragma unroll
    for (int i = 0; i < 4; ++i)
      #pragma unroll
      for (int j = 0; j < 4; ++j)
        S[(size_t)(bi + ty * 4 + i) * NN + bj + tx * 4 + j] = acc[i][j];
  }
}

// ---------------------------------------------------------------- gated: top-50 per row (row-loop)
__global__ __launch_bounds__(256) void k_topk(const float* __restrict__ sim,
                                              float* __restrict__ vals,
                                              int* __restrict__ idxo,
                                              const int* __restrict__ gate) {
  if (gate[0] == 0) return;
  const int t = threadIdx.x;
  __shared__ float sv[NN];
  __shared__ float bw[4];
  __shared__ int bj4[4];
  for (int row = blockIdx.x; row < NN; row += gridDim.x) {
    const float* sr = sim + (size_t)row * NN;
    for (int j = t; j < NN; j += 256) sv[j] = sr[j];
    __syncthreads();
    for (int it = 0; it < KTOP; ++it) {
      float bv = -3.4e38f; int bj = NN;
      for (int j = t; j < NN; j += 256) {
        const float v = sv[j];
        if (v > bv || (v == bv && j < bj)) { bv = v; bj = j; }
      }
      #pragma unroll
      for (int o = 32; o; o >>= 1) {
        const float ov = __shfl_down(bv, o);
        const int oj = __shfl_down(bj, o);
        if (ov > bv || (ov == bv && oj < bj)) { bv = ov; bj = oj; }
      }
      if ((t & 63) == 0) { bw[t >> 6] = bv; bj4[t >> 6] = bj; }
      __syncthreads();
      if (t == 0) {
        #pragma unroll
        for (int q = 1; q < 4; ++q)
          if (bw[q] > bv || (bw[q] == bv && bj4[q] < bj)) { bv = bw[q]; bj = bj4[q]; }
        vals[row * KTOP + it] = bv;
        idxo[row * KTOP + it] = bj;
        sv[bj] = -3.4e38f;
      }
      __syncthreads();
    }
  }
}

// ---------------------------------------------------------------- gated: zero A_new region (grid-stride)
__global__ __launch_bounds__(256) void k_zero(float* __restrict__ p, const int* __restrict__ gate) {
  if (gate[0] == 0) return;
  const size_t stride = (size_t)gridDim.x * 256;
  for (size_t i = (size_t)blockIdx.x * 256 + threadIdx.x; i < (size_t)NN * NN / 4; i += stride)
    ((f32x4*)p)[i] = f32x4{0.f, 0.f, 0.f, 0.f};
}

// ---------------------------------------------------------------- gated: scatter-symmetrize (grid-stride)
__global__ __launch_bounds__(256) void k_scatter(const float* __restrict__ vals,
                                                 const int* __restrict__ idx,
                                                 float* __restrict__ anew,
                                                 const int* __restrict__ gate) {
  if (gate[0] == 0) return;
  const int stride = gridDim.x * 256;
  for (int tid = blockIdx.x * 256 + threadIdx.x; tid < NN * KTOP; tid += stride) {
    const int i = tid / KTOP;
    const float v = vals[tid] * 0.5f;
    const int j = idx[tid];
    atomicAdd(anew + (size_t)i * NN + j, v);
    atomicAdd(anew + (size_t)j * NN + i, v);
  }
}

// ---------------------------------------------------------------- mask + fuse + row sums + bf16 sidecar (always)
__device__ __forceinline__ float maskval(float a, float ev, float di, float m0) {
  if (a > 0.0f) {
    const float w = 2.0f / (1.0f + expf(di - ev));
    return (w >= 1.0f) ? a * w : 0.0f;
  }
  return a * m0;
}

__global__ __launch_bounds__(256) void k_mask_final(float* __restrict__ anew,
                                                    const float* __restrict__ adj,
                                                    const float* __restrict__ e,
                                                    const float* __restrict__ delta,
                                                    float* __restrict__ afin,
                                                    ushort* __restrict__ afb,
                                                    float* __restrict__ dinv2f,
                                                    const int* __restrict__ gate) {
  const int row = blockIdx.x, t = threadIdx.x;
  const bool fl = gate[0] != 0;
  const float di = delta[row];
  const float w0 = 2.0f / (1.0f + expf(di));
  const float m0 = (w0 >= 1.0f) ? w0 : 0.0f;
  const f32x4* ar = (const f32x4*)(adj + (size_t)row * NN);
  f32x4* an = (f32x4*)(anew + (size_t)row * NN);
  f32x4* af = (f32x4*)(afin + (size_t)row * NN);
  ushort* ab = afb + (size_t)row * NN;
  const f32x4* ef = (const f32x4*)e;
  float s = 0.f;
  for (int q = t; q < NN / 4; q += 256) {
    f32x4 a = fl ? an[q] : f32x4{0.f, 0.f, 0.f, 0.f};
    const f32x4 ad = ar[q];
    const f32x4 ev = ef[q];
    f32x4 ao, fo;
    ao.x = maskval(a.x, ev.x, di, m0); fo.x = ao.x + ad.x;
    ao.y = maskval(a.y, ev.y, di, m0); fo.y = ao.y + ad.y;
    ao.z = maskval(a.z, ev.z, di, m0); fo.z = ao.z + ad.z;
    ao.w = maskval(a.w, ev.w, di, m0); fo.w = ao.w + ad.w;
    s += fo.x + fo.y + fo.z + fo.w;
    __builtin_nontemporal_store(ao, an + q);
    __builtin_nontemporal_store(fo, af + q);
    u16x4 hb;
    hb.x = f2b(fo.x); hb.y = f2b(fo.y); hb.z = f2b(fo.z); hb.w = f2b(fo.w);
    __builtin_nontemporal_store(hb, (u16x4*)(ab + q * 4));
  }
  s = wave_sum(s);
  __shared__ float sm[4];
  if ((t & 63) == 0) sm[t >> 6] = s;
  __syncthreads();
  if (t == 0) {
    const float tot = sm[0] + sm[1] + sm[2] + sm[3];
    dinv2f[row] = tot > 0.f ? 1.0f / sqrtf(tot) : 0.0f;
  }
}

// ---------------------------------------------------------------- GEMM-A: Y1T = bf16(dinv2 (.) (input @ W1))^T, direct
// 32x128 tile: wave (rowg=w&1, colg=w>>1); grid 192
__global__ __launch_bounds__(256) void k_gA(const float* __restrict__ in,
                                            const ushort* __restrict__ W1T,
                                            const float* __restrict__ dinv2,
                                            ushort* __restrict__ Y1T) {
  const int wave = threadIdx.x >> 6, lane = threadIdx.x & 63;
  const int m0 = blockIdx.x * 32 + (wave & 1) * 16;
  const int c0 = (wave >> 1) * 64;
  const int r = lane & 15, kg = lane >> 4;
  f32x4 acc[4];
  #pragma unroll
  for (int i = 0; i < 4; ++i) acc[i] = f32x4{0.f, 0.f, 0.f, 0.f};
  const float* a_ptr = in + (size_t)(m0 + r) * FF + kg * 8;
  const ushort* b_ptr = W1T + (size_t)(c0 + r) * FF + kg * 8;
  #pragma unroll 2
  for (int k = 0; k < FF; k += 32) {
    const float4 f0 = *(const float4*)(a_ptr + k);
    const float4 f1 = *(const float4*)(a_ptr + k + 4);
    bf16x8 av;
    av[0] = (short)f2b(f0.x); av[1] = (short)f2b(f0.y);
    av[2] = (short)f2b(f0.z); av[3] = (short)f2b(f0.w);
    av[4] = (short)f2b(f1.x); av[5] = (short)f2b(f1.y);
    av[6] = (short)f2b(f1.z); av[7] = (short)f2b(f1.w);
    #pragma unroll
    for (int nb = 0; nb < 4; ++nb) {
      const bf16x8 bv = *(const bf16x8*)(b_ptr + (size_t)nb * 16 * FF + k);
      acc[nb] = __builtin_amdgcn_mfma_f32_16x16x32_bf16(av, bv, acc[nb], 0, 0, 0);
    }
  }
  const int mb = m0 + kg * 4;
  const float4 dv = *(const float4*)(dinv2 + mb);
  #pragma unroll
  for (int nb = 0; nb < 4; ++nb) {
    const int c = c0 + nb * 16 + r;
    u16x4 hb;
    hb.x = f2b(acc[nb][0] * dv.x); hb.y = f2b(acc[nb][1] * dv.y);
    hb.z = f2b(acc[nb][2] * dv.z); hb.w = f2b(acc[nb][3] * dv.w);
    *(u16x4*)(Y1T + (size_t)c * NN + mb) = hb;
  }
}

// ---------------------------------------------------------------- GEMM-B: P[z] = AFINB @ Y1T^T, 32x128 tiles, split-K
template <int SPLITS>
__global__ __launch_bounds__(256) void k_gB(const ushort* __restrict__ A,
                                            const ushort* __restrict__ BT,
                                            float* __restrict__ P) {
  const int wave = threadIdx.x >> 6, lane = threadIdx.x & 63;
  const int m0 = blockIdx.x * 32 + (wave & 1) * 16;
  const int c0 = (wave >> 1) * 64;
  const int klen = NN / SPLITS;
  const int kbeg = blockIdx.z * klen;
  const int r = lane & 15, kg = lane >> 4;
  f32x4 acc[4];
  #pragma unroll
  for (int i = 0; i < 4; ++i) acc[i] = f32x4{0.f, 0.f, 0.f, 0.f};
  const ushort* a_ptr = A + (size_t)(m0 + r) * NN + kbeg + kg * 8;
  const ushort* b_ptr = BT + (size_t)(c0 + r) * NN + kbeg + kg * 8;
  #pragma unroll 4
  for (int k = 0; k < klen; k += 32) {
    const bf16x8 av = *(const bf16x8*)(a_ptr + k);
    #pragma unroll
    for (int nb = 0; nb < 4; ++nb) {
      const bf16x8 bv = *(const bf16x8*)(b_ptr + (size_t)nb * 16 * NN + k);
      acc[nb] = __builtin_amdgcn_mfma_f32_16x16x32_bf16(av, bv, acc[nb], 0, 0, 0);
    }
  }
  float* Pz = P + (size_t)blockIdx.z * NN * HH;
  #pragma unroll
  for (int nb = 0; nb < 4; ++nb)
    #pragma unroll
    for (int i = 0; i < 4; ++i)
      Pz[(size_t)(m0 + kg * 4 + i) * HH + c0 + nb * 16 + r] = acc[nb][i];
}

// ---------------------------------------------------------------- GEMM-C: Y2T = bf16(dinv2 (.) (XRELU @ W2))^T, direct
__global__ __launch_bounds__(256) void k_gC(const ushort* __restrict__ XR,
                                            const ushort* __restrict__ W2T,
                                            const float* __restrict__ dinv2,
                                            ushort* __restrict__ Y2T) {
  const int wave = threadIdx.x >> 6, lane = threadIdx.x & 63;
  const int mw = blockIdx.x * 64 + wave * 16;
  const int r = lane & 15, kg = lane >> 4;
  f32x4 acc = f32x4{0.f, 0.f, 0.f, 0.f};
  const ushort* a_ptr = XR + (size_t)(mw + r) * HH + kg * 8;
  const ushort* b_ptr = W2T + (size_t)r * HH + kg * 8;
  #pragma unroll
  for (int k = 0; k < HH; k += 32) {
    const bf16x8 av = *(const bf16x8*)(a_ptr + k);
    const bf16x8 bv = *(const bf16x8*)(b_ptr + k);
    acc = __builtin_amdgcn_mfma_f32_16x16x32_bf16(av, bv, acc, 0, 0, 0);
  }
  const int mb = mw + kg * 4;
  const float4 dv = *(const float4*)(dinv2 + mb);
  u16x4 hb;
  hb.x = f2b(acc[0] * dv.x); hb.y = f2b(acc[1] * dv.y);
  hb.z = f2b(acc[2] * dv.z); hb.w = f2b(acc[3] * dv.w);
  *(u16x4*)(Y2T + (size_t)r * NN + mb) = hb;
}

// ---------------------------------------------------------------- GEMM-D: P[z] = AFINB @ Y2T^T, 16-row waves, split-K
template <int SPLITS>
__global__ __launch_bounds__(256) void k_gD(const ushort* __restrict__ A,
                                            const ushort* __restrict__ BT,
                                            float* __restrict__ P) {
  const int wave = threadIdx.x >> 6, lane = threadIdx.x & 63;
  const int m0 = blockIdx.x * 64 + wave * 16;
  const int klen = NN / SPLITS;
  const int kbeg = blockIdx.z * klen;
  const int r = lane & 15, kg = lane >> 4;
  f32x4 acc = f32x4{0.f, 0.f, 0.f, 0.f};
  const ushort* a_ptr = A + (size_t)(m0 + r) * NN + kbeg + kg * 8;
  const ushort* b_ptr = BT + (size_t)r * NN + kbeg + kg * 8;
  #pragma unroll 4
  for (int k = 0; k < klen; k += 32) {
    const bf16x8 av = *(const bf16x8*)(a_ptr + k);
    const bf16x8 bv = *(const bf16x8*)(b_ptr + k);
    acc = __builtin_amdgcn_mfma_f32_16x16x32_bf16(av, bv, acc, 0, 0, 0);
  }
  float* Pz = P + (size_t)blockIdx.z * NN * CCC;
  #pragma unroll
  for (int i = 0; i < 4; ++i)
    Pz[(size_t)(m0 + kg * 4 + i) * CCC + r] = acc[i];
}

// ---------------------------------------------------------------- split-K reduce + epilogue + optional bf16 emit
// MODE: 3 = relu(v*rs+bias) ; 4 = v*rs+bias.  EMIT: 0 none, 2 row-major bf16
template <int MODE, int EMIT>
__global__ __launch_bounds__(256) void k_reduce(const float* __restrict__ P,
                                                float* __restrict__ C,
                                                const float* __restrict__ rs,
                                                const float* __restrict__ bias,
                                                int M, int NC, int S,
                                                ushort* __restrict__ bt) {
  const size_t idx = (size_t)blockIdx.x * 256 + threadIdx.x;
  const size_t tot = (size_t)M * NC;
  float s = 0.f;
  for (int p = 0; p < S; ++p) s += P[p * tot + idx];
  const int r = (int)(idx / NC), c = (int)(idx % NC);
  float v = s * rs[r] + bias[c];
  if constexpr (MODE == 3) v = v > 0.f ? v : 0.f;
  if (C) C[idx] = v;
  if constexpr (EMIT == 2) bt[idx] = f2b(v);
}

// ---------------------------------------------------------------- launcher
extern "C" void kernel_launch(void* const* d_in, const int* in_sizes, int n_in,
                              void* d_out, int out_size, void* d_ws, size_t ws_size,
                              hipStream_t stream) {
  const float* input = (const float*)d_in[0];
  const float* Adj   = (const float*)d_in[1];
  const float* unc   = (const float*)d_in[2];
  const float* w1    = (const float*)d_in[3];
  const float* w2    = (const float*)d_in[4];
  const float* delta = (const float*)d_in[5];
  const float* W1    = (const float*)d_in[6];
  const float* b1    = (const float*)d_in[7];
  const float* W2    = (const float*)d_in[8];
  const float* b2    = (const float*)d_in[9];

  float* xout = (float*)d_out;
  float* anew = xout + (size_t)NN * CCC;
  float* afin = anew + (size_t)NN * NN;

  float* w = (float*)d_ws;
  size_t o = 0;
  float* DINV  = w + o; o += NN;
  float* DSQ   = w + o; o += NN;
  float* EARR  = w + o; o += NN;
  float* DINV2 = w + o; o += NN;
  int*   FLAG  = (int*)(w + o); o += NN;
  // union region: gated scratch chain OR bf16 A_final sidecar (chain dead by then)
  float* REGION = w + o; o += (size_t)NN * NN / 2;          // NN*NN ushorts
  float* X1   = REGION;
  float* X2   = X1 + (size_t)NN * FF;
  float* EMBP = X2 + (size_t)NN * FF;
  float* EMBN = EMBP + (size_t)NN * FF;
  float* VALS = EMBN + (size_t)NN * FF;
  int*   IDX  = (int*)(VALS + (size_t)NN * KTOP);
  ushort* AFINB = (ushort*)REGION;
  ushort* Y1T    = (ushort*)(w + o); o += (size_t)NN * HH / 2;    // [128][6144]
  ushort* XRELUB = (ushort*)(w + o); o += (size_t)NN * HH / 2;    // [6144][128]
  ushort* Y2T    = (ushort*)(w + o); o += (size_t)NN * CCC / 2;   // [16][6144]
  ushort* W1T    = (ushort*)(w + o); o += (size_t)FF * HH / 2;    // [128][512]
  ushort* W2T    = (ushort*)(w + o); o += (size_t)HH * CCC / 2 + 64;
  float* PK      = w + o; o += (size_t)4 * NN * HH;               // split-K partials (12.6 MB, shared B/D)

  // flag + e + weight transposes
  k_flag_prep<<<257, 256, 0, stream>>>(unc, delta, EARR, FLAG, W1, W2, W1T, W2T);

  // ---- gated graph-revision chain (dead unless some exp(-u_j) >= min delta) ----
  k_rowsum_prescale<<<128, 256, 0, stream>>>(Adj, input, w1, DINV, DSQ, X1, FLAG);
  k_gemm<2><<<128, 256, 0, stream>>>(Adj, X1, X2, DSQ, w2, NN, NN, FF, FLAG);
  k_gemm<0><<<128, 256, 0, stream>>>(Adj, X2, EMBP, nullptr, nullptr, NN, NN, FF, FLAG);
  k_normalize<<<128, 256, 0, stream>>>(EMBP, DINV, EMBN, FLAG);
  k_sim<<<256, 256, 0, stream>>>(EMBN, afin, FLAG);               // sim scratch in A_final region
  k_topk<<<128, 256, 0, stream>>>(afin, VALS, IDX, FLAG);
  k_zero<<<256, 256, 0, stream>>>(anew, FLAG);
  k_scatter<<<128, 256, 0, stream>>>(VALS, IDX, anew, FLAG);

  // ---- mask, fuse with Adj, row sums of A_final, bf16 sidecar (always) ----
  k_mask_final<<<NN, 256, 0, stream>>>(anew, Adj, EARR, delta, afin, AFINB, DINV2, FLAG);

  // ---- task GCN, all-MFMA ----
  k_gA<<<192, 256, 0, stream>>>(input, W1T, DINV2, Y1T);
  k_gB<4><<<dim3(192, 1, 4), 256, 0, stream>>>(AFINB, Y1T, PK);
  k_reduce<3, 2><<<(NN * HH) / 256, 256, 0, stream>>>(PK, nullptr, DINV2, b1, NN, HH, 4, XRELUB);
  k_gC<<<96, 256, 0, stream>>>(XRELUB, W2T, DINV2, Y2T);
  k_gD<16><<<dim3(96, 1, 16), 256, 0, stream>>>(AFINB, Y2T, PK);
  k_reduce<4, 0><<<(NN * CCC) / 256, 256, 0, stream>>>(PK, xout, DINV2, b2, NN, CCC, 16, nullptr);
}